// Round 2
// baseline (1164.423 us; speedup 1.0000x reference)
//
#include <hip/hip_runtime.h>
#include <hip/hip_bf16.h>

#define SLOPE 0.2f
#define EPS_GN 1e-5f

__device__ __forceinline__ float lrelu(float v) { return v > 0.f ? v : SLOPE * v; }
__device__ __forceinline__ unsigned int flipf(float x) {
    unsigned int u = __float_as_uint(x);
    return (u & 0x80000000u) ? ~u : (u | 0x80000000u);
}
__device__ __forceinline__ float unflipf(unsigned int u) {
    return __uint_as_float((u & 0x80000000u) ? (u & 0x7fffffffu) : ~u);
}

// ---------------- weight prep: WT1 = (w1@enc_w)^T (k-major), bc1 = w1@enc_b ----
__global__ void prep_weights(const float* __restrict__ enc_w,
                             const float* __restrict__ enc_b,
                             const float* __restrict__ w1,
                             const float* __restrict__ w2,
                             float* __restrict__ WT1, float* __restrict__ WT2,
                             float* __restrict__ bc1, float* __restrict__ bc2) {
    int c = blockIdx.x;   // 128 blocks (output channel)
    int k = threadIdx.x;  // 128 threads (input channel)
    __shared__ float w1row[128];
    w1row[k] = w1[c * 128 + k];
    __syncthreads();
    float acc = 0.f;
    for (int j = 0; j < 128; ++j)
        acc = fmaf(w1row[j], enc_w[j * 128 + k], acc);
    WT1[k * 128 + c] = acc;
    WT2[k * 128 + c] = w2[c * 128 + k];
    if (k == 0) {
        float b = 0.f;
        for (int j = 0; j < 128; ++j) b += w1row[j] * enc_b[j];
        bc1[c] = b;
        bc2[c] = 0.f;
    }
}

// ---------------- CSR build ----------------
__global__ void count_deg(const int* __restrict__ ei, int* __restrict__ deg, int E, int N) {
    int e = blockIdx.x * 256 + threadIdx.x;
    if (e >= E + N) return;
    int dst = (e < E) ? ei[E + e] : (e - E);
    atomicAdd(&deg[dst], 1);
}

__global__ void scan_block_sums(const int* __restrict__ deg, int* __restrict__ part, int N) {
    __shared__ int sh[256];
    int t = threadIdx.x;
    int i = blockIdx.x * 256 + t;
    sh[t] = (i < N) ? deg[i] : 0;
    __syncthreads();
    for (int off = 128; off; off >>= 1) {
        if (t < off) sh[t] += sh[t + off];
        __syncthreads();
    }
    if (t == 0) part[blockIdx.x] = sh[0];
}

__global__ void scan_partials(int* __restrict__ part, int nb) {
    __shared__ int sh[1024];
    int t = threadIdx.x;
    int v = (t < nb) ? part[t] : 0;
    sh[t] = v;
    __syncthreads();
    for (int off = 1; off < 1024; off <<= 1) {
        int add = (t >= off) ? sh[t - off] : 0;
        __syncthreads();
        sh[t] += add;
        __syncthreads();
    }
    if (t < nb) part[t] = sh[t] - v;  // exclusive
}

__global__ void scan_write(const int* __restrict__ deg, const int* __restrict__ part,
                           int* __restrict__ row, int* __restrict__ cursor, int N, int Etot) {
    __shared__ int sh[256];
    int t = threadIdx.x;
    int i = blockIdx.x * 256 + t;
    int v = (i < N) ? deg[i] : 0;
    sh[t] = v;
    __syncthreads();
    for (int off = 1; off < 256; off <<= 1) {
        int add = (t >= off) ? sh[t - off] : 0;
        __syncthreads();
        sh[t] += add;
        __syncthreads();
    }
    int excl = sh[t] - v + part[blockIdx.x];
    if (i < N) { row[i] = excl; cursor[i] = excl; }
    if (i == 0 && blockIdx.x == 0) row[N] = Etot;
}

__global__ void scatter_edges(const int* __restrict__ ei, int* __restrict__ cursor,
                              int* __restrict__ esrc, int E, int N) {
    int e = blockIdx.x * 256 + threadIdx.x;
    if (e >= E + N) return;
    int src, dst;
    if (e < E) { src = ei[e]; dst = ei[E + e]; } else { src = dst = e - E; }
    int pos = atomicAdd(&cursor[dst], 1);
    esrc[pos] = src;
}

// ---------------- GEMM: H[N,128] = A[N,128] @ WT + bias; plus att scores ------
// one wave per node-slice; lane owns channels 2*lane, 2*lane+1; WT fp32 in LDS
__global__ void __launch_bounds__(256) gemm_kernel(
    const float* __restrict__ A, const float* __restrict__ WT,
    const float* __restrict__ bias, const float* __restrict__ att_src,
    const float* __restrict__ att_dst,
    float* __restrict__ H, float* __restrict__ ssrc, float* __restrict__ sdst, int N) {
    __shared__ float wtb[128 * 128];  // 64 KB, [k][c]
    __shared__ float arow[4][128];
    __shared__ float asrc_s[128], adst_s[128];
    int tid = threadIdx.x;
    for (int idx = tid; idx < 128 * 32; idx += 256)
        ((float4*)wtb)[idx] = ((const float4*)WT)[idx];
    if (tid < 128) {
        asrc_s[tid] = att_src[tid];
        adst_s[tid] = att_dst[tid];
    }
    __syncthreads();
    int w = tid >> 6, lane = tid & 63;
    int c0 = lane * 2;
    for (int it = 0; it < 8; ++it) {
        int n = blockIdx.x * 32 + it * 4 + w;
        if (n < N) {
            ((float2*)arow[w])[lane] = ((const float2*)A)[n * 64 + lane];
            float acc0 = bias[c0], acc1 = bias[c0 + 1];
#pragma unroll
            for (int k = 0; k < 128; ++k) {
                float a = arow[w][k];
                acc0 = fmaf(a, wtb[k * 128 + c0], acc0);
                acc1 = fmaf(a, wtb[k * 128 + c0 + 1], acc1);
            }
            ((float2*)H)[n * 64 + lane] = make_float2(acc0, acc1);
            float vs = fmaf(acc0, asrc_s[c0], acc1 * asrc_s[c0 + 1]);
            float vd = fmaf(acc0, adst_s[c0], acc1 * adst_s[c0 + 1]);
#pragma unroll
            for (int off = 8; off; off >>= 1) {
                vs += __shfl_xor(vs, off, 16);
                vd += __shfl_xor(vd, off, 16);
            }
            if ((lane & 15) == 0) {
                int h = lane >> 4;
                ssrc[n * 4 + h] = vs;
                sdst[n * 4 + h] = vd;
            }
        }
    }
}

// ---------------- aggregation: per-dst softmax + weighted sum, wave per node --
__global__ void __launch_bounds__(256) agg_kernel(
    const int* __restrict__ row, const int* __restrict__ esrc,
    const float* __restrict__ ssrc, const float* __restrict__ sdst,
    const float* __restrict__ H, const float* __restrict__ bias,
    float* __restrict__ out, int N) {
    int n = (blockIdx.x * 256 + threadIdx.x) >> 6;
    int lane = threadIdx.x & 63;
    if (n >= N) return;
    int beg = row[n], end = row[n + 1];
    float4 sd = ((const float4*)sdst)[n];

    // phase A: per-head max over incoming edges
    float m0 = -3e38f, m1 = -3e38f, m2 = -3e38f, m3 = -3e38f;
    for (int e = beg + lane; e < end; e += 64) {
        int s = esrc[e];
        float4 ss = ((const float4*)ssrc)[s];
        m0 = fmaxf(m0, lrelu(ss.x + sd.x));
        m1 = fmaxf(m1, lrelu(ss.y + sd.y));
        m2 = fmaxf(m2, lrelu(ss.z + sd.z));
        m3 = fmaxf(m3, lrelu(ss.w + sd.w));
    }
#pragma unroll
    for (int off = 32; off; off >>= 1) {
        m0 = fmaxf(m0, __shfl_xor(m0, off));
        m1 = fmaxf(m1, __shfl_xor(m1, off));
        m2 = fmaxf(m2, __shfl_xor(m2, off));
        m3 = fmaxf(m3, __shfl_xor(m3, off));
    }
    // phase A2: denom
    float d0 = 0.f, d1 = 0.f, d2 = 0.f, d3 = 0.f;
    for (int e = beg + lane; e < end; e += 64) {
        int s = esrc[e];
        float4 ss = ((const float4*)ssrc)[s];
        d0 += __expf(lrelu(ss.x + sd.x) - m0);
        d1 += __expf(lrelu(ss.y + sd.y) - m1);
        d2 += __expf(lrelu(ss.z + sd.z) - m2);
        d3 += __expf(lrelu(ss.w + sd.w) - m3);
    }
#pragma unroll
    for (int off = 32; off; off >>= 1) {
        d0 += __shfl_xor(d0, off);
        d1 += __shfl_xor(d1, off);
        d2 += __shfl_xor(d2, off);
        d3 += __shfl_xor(d3, off);
    }
    // phase B: lane owns channels 2*lane, 2*lane+1 (head = lane>>4)
    int hh = lane >> 4;
    float mh = hh < 2 ? (hh == 0 ? m0 : m1) : (hh == 2 ? m2 : m3);
    float dh = hh < 2 ? (hh == 0 ? d0 : d1) : (hh == 2 ? d2 : d3);
    float sdh = hh < 2 ? (hh == 0 ? sd.x : sd.y) : (hh == 2 ? sd.z : sd.w);
    float rh = 1.f / dh;
    int c0 = lane * 2;
    float a0 = 0.f, a1 = 0.f;
    for (int e = beg; e < end; ++e) {
        int s = esrc[e];
        float al = __expf(lrelu(ssrc[s * 4 + hh] + sdh) - mh) * rh;
        float2 hv = ((const float2*)H)[s * 64 + lane];
        a0 = fmaf(al, hv.x, a0);
        a1 = fmaf(al, hv.y, a1);
    }
    a0 += bias[c0];
    a1 += bias[c0 + 1];
    a0 = a0 > 0.f ? a0 : __expf(a0) - 1.f;  // ELU
    a1 = a1 > 0.f ? a1 : __expf(a1) - 1.f;
    ((float2*)out)[n * 64 + lane] = make_float2(a0, a1);
}

// ---------------- GraphNorm ----------------
__global__ void norm_stats(const float* __restrict__ X, const int* __restrict__ batch,
                           float* __restrict__ gsum, float* __restrict__ gsq,
                           int* __restrict__ gcnt, int N, int countFlag) {
    int c = threadIdx.x;  // 128
    int base = blockIdx.x * 64;
    if (base >= N) return;
    int end = min(base + 64, N);
    int cur = batch[base];
    float s = 0.f, q = 0.f;
    int cnt = 0;
    for (int n = base; n < end; ++n) {
        int g = batch[n];
        if (g != cur) {
            atomicAdd(&gsum[cur * 128 + c], s);
            atomicAdd(&gsq[cur * 128 + c], q);
            if (c == 0 && countFlag) atomicAdd(&gcnt[cur], cnt);
            s = 0.f; q = 0.f; cnt = 0; cur = g;
        }
        float v = X[n * 128 + c];
        s += v;
        q += v * v;
        ++cnt;
    }
    atomicAdd(&gsum[cur * 128 + c], s);
    atomicAdd(&gsq[cur * 128 + c], q);
    if (c == 0 && countFlag) atomicAdd(&gcnt[cur], cnt);
}

__global__ void norm_coef(const float* __restrict__ gsum, const float* __restrict__ gsq,
                          const int* __restrict__ gcnt,
                          const float* __restrict__ w, const float* __restrict__ b,
                          const float* __restrict__ ms,
                          float* __restrict__ Ac, float* __restrict__ Bc) {
    int g = blockIdx.x, c = threadIdx.x;
    int i = g * 128 + c;
    float cntv = (float)gcnt[g];
    if (cntv < 0.5f) { Ac[i] = 0.f; Bc[i] = 0.f; return; }
    float mean = gsum[i] / cntv;
    float msv = ms[c];
    float var = gsq[i] / cntv - msv * (2.f - msv) * mean * mean;
    var = fmaxf(var, 0.f);
    float inv = rsqrtf(var + EPS_GN);
    float wv = w[c];
    Ac[i] = wv * inv;
    Bc[i] = b[c] - msv * mean * wv * inv;
}

__global__ void norm_apply(float* __restrict__ X, const int* __restrict__ batch,
                           const float* __restrict__ Ac, const float* __restrict__ Bc, int N) {
    int idx = blockIdx.x * 256 + threadIdx.x;  // over N*64 float2 pairs
    if (idx >= N * 64) return;
    int n = idx >> 6, cp = idx & 63;
    int g = batch[n];
    float2* X2 = (float2*)X;
    float2 v = X2[idx];
    float2 a = ((const float2*)Ac)[g * 64 + cp];
    float2 b = ((const float2*)Bc)[g * 64 + cp];
    X2[idx] = make_float2(fmaf(v.x, a.x, b.x), fmaf(v.y, a.y, b.y));
}

// layer-2 normalize fused with segment-max pooling (flip-encoded atomicMax)
__global__ void norm_pool(const float* __restrict__ X, const int* __restrict__ batch,
                          const float* __restrict__ Ac, const float* __restrict__ Bc,
                          unsigned int* __restrict__ pool, int N) {
    int c = threadIdx.x;  // 128
    int base = blockIdx.x * 64;
    if (base >= N) return;
    int end = min(base + 64, N);
    int cur = batch[base];
    float mx = -3e38f;
    for (int n = base; n < end; ++n) {
        int g = batch[n];
        if (g != cur) {
            atomicMax(&pool[cur * 128 + c], flipf(mx));
            mx = -3e38f;
            cur = g;
        }
        float v = fmaf(X[n * 128 + c], Ac[g * 128 + c], Bc[g * 128 + c]);
        mx = fmaxf(mx, v);
    }
    atomicMax(&pool[cur * 128 + c], flipf(mx));
}

// ---------------- FC: out[g][o] = pooled[g] . fc_w[o] + fc_b[o] --------------
__global__ void fc_kernel(const unsigned int* __restrict__ pool,
                          const float* __restrict__ fcw,
                          const float* __restrict__ fcb,
                          float* __restrict__ out) {
    int g = blockIdx.x, o = threadIdx.x;  // 64 x 64
    __shared__ float p[128];
    p[o] = unflipf(pool[g * 128 + o]);
    p[o + 64] = unflipf(pool[g * 128 + 64 + o]);
    __syncthreads();
    float acc = fcb[o];
    for (int k = 0; k < 128; ++k)
        acc = fmaf(p[k], fcw[o * 128 + k], acc);
    out[g * 64 + o] = acc;
}

extern "C" void kernel_launch(void* const* d_in, const int* in_sizes, int n_in,
                              void* d_out, int out_size, void* d_ws, size_t ws_size,
                              hipStream_t stream) {
    const float* x     = (const float*)d_in[0];
    const int* ei      = (const int*)d_in[1];
    const int* batch   = (const int*)d_in[2];
    const float* enc_w = (const float*)d_in[3];
    const float* enc_b = (const float*)d_in[4];
    const float* w1    = (const float*)d_in[5];
    const float* as1   = (const float*)d_in[6];
    const float* ad1   = (const float*)d_in[7];
    const float* b1    = (const float*)d_in[8];
    const float* n1w   = (const float*)d_in[9];
    const float* n1b   = (const float*)d_in[10];
    const float* n1ms  = (const float*)d_in[11];
    const float* w2    = (const float*)d_in[12];
    const float* as2   = (const float*)d_in[13];
    const float* ad2   = (const float*)d_in[14];
    const float* b2    = (const float*)d_in[15];
    const float* n2w   = (const float*)d_in[16];
    const float* n2b   = (const float*)d_in[17];
    const float* n2ms  = (const float*)d_in[18];
    const float* fcw   = (const float*)d_in[19];
    const float* fcb   = (const float*)d_in[20];
    float* out = (float*)d_out;

    int N = in_sizes[2];
    int E = in_sizes[1] / 2;
    int Etot = E + N;

    char* ws = (char*)d_ws;
    size_t off = 0;
    auto take = [&](size_t bytes) {
        char* p = ws + off;
        off = (off + bytes + 255) & ~(size_t)255;
        return p;
    };
    float* WT1 = (float*)take(128 * 128 * 4);
    float* WT2 = (float*)take(128 * 128 * 4);
    float* bc1 = (float*)take(512);
    float* bc2 = (float*)take(512);
    float* ssrc = (float*)take((size_t)N * 16);
    float* sdst = (float*)take((size_t)N * 16);
    int* deg    = (int*)take((size_t)N * 4);
    int* rowp   = (int*)take((size_t)(N + 1) * 4);
    int* cursor = (int*)take((size_t)N * 4);
    int* part   = (int*)take(4096 * 4);
    int* esrc   = (int*)take((size_t)Etot * 4);
    float* H    = (float*)take((size_t)N * 512);
    float* AG   = (float*)take((size_t)N * 512);
    float* gsum = (float*)take(64 * 128 * 4);
    float* gsq  = (float*)take(64 * 128 * 4);
    int* gcnt   = (int*)take(256);
    float* Ac   = (float*)take(64 * 128 * 4);
    float* Bc   = (float*)take(64 * 128 * 4);
    unsigned int* pool = (unsigned int*)take(64 * 128 * 4);
    if (off > ws_size) return;  // workspace too small -> output stays zero

    int NB = (N + 255) / 256;

    prep_weights<<<128, 128, 0, stream>>>(enc_w, enc_b, w1, w2, WT1, WT2, bc1, bc2);

    hipMemsetAsync(deg, 0, (size_t)N * 4, stream);
    count_deg<<<(Etot + 255) / 256, 256, 0, stream>>>(ei, deg, E, N);
    scan_block_sums<<<NB, 256, 0, stream>>>(deg, part, N);
    scan_partials<<<1, 1024, 0, stream>>>(part, NB);
    scan_write<<<NB, 256, 0, stream>>>(deg, part, rowp, cursor, N, Etot);
    scatter_edges<<<(Etot + 255) / 256, 256, 0, stream>>>(ei, cursor, esrc, E, N);

    // ---- layer 1 (encoder folded into W) ----
    gemm_kernel<<<(N + 31) / 32, 256, 0, stream>>>(x, WT1, bc1, as1, ad1, H, ssrc, sdst, N);
    agg_kernel<<<(N + 3) / 4, 256, 0, stream>>>(rowp, esrc, ssrc, sdst, H, b1, AG, N);
    hipMemsetAsync(gsum, 0, 32768, stream);
    hipMemsetAsync(gsq, 0, 32768, stream);
    hipMemsetAsync(gcnt, 0, 256, stream);
    norm_stats<<<(N + 63) / 64, 128, 0, stream>>>(AG, batch, gsum, gsq, gcnt, N, 1);
    norm_coef<<<64, 128, 0, stream>>>(gsum, gsq, gcnt, n1w, n1b, n1ms, Ac, Bc);
    norm_apply<<<(N * 64 + 255) / 256, 256, 0, stream>>>(AG, batch, Ac, Bc, N);

    // ---- layer 2 ----
    gemm_kernel<<<(N + 31) / 32, 256, 0, stream>>>(AG, WT2, bc2, as2, ad2, H, ssrc, sdst, N);
    agg_kernel<<<(N + 3) / 4, 256, 0, stream>>>(rowp, esrc, ssrc, sdst, H, b2, AG, N);
    hipMemsetAsync(gsum, 0, 32768, stream);
    hipMemsetAsync(gsq, 0, 32768, stream);
    hipMemsetAsync(pool, 0, 32768, stream);
    norm_stats<<<(N + 63) / 64, 128, 0, stream>>>(AG, batch, gsum, gsq, gcnt, N, 0);
    norm_coef<<<64, 128, 0, stream>>>(gsum, gsq, gcnt, n2w, n2b, n2ms, Ac, Bc);
    norm_pool<<<(N + 63) / 64, 128, 0, stream>>>(AG, batch, Ac, Bc, pool, N);

    fc_kernel<<<64, 64, 0, stream>>>(pool, fcw, fcb, out);
}

// Round 3
// 852.198 us; speedup vs baseline: 1.3664x; 1.3664x over previous
//
#include <hip/hip_runtime.h>
#include <hip/hip_bf16.h>

#define SLOPE 0.2f
#define EPS_GN 1e-5f
#define APITCH 136  // LDS row pitch in bf16 elements (272 B): breaks 256B-stride bank aliasing to 2-way (free)

typedef __attribute__((ext_vector_type(8))) short bfrag;   // 8 bf16 = 4 VGPR (MFMA A/B operand)
typedef __attribute__((ext_vector_type(4))) float ffrag;   // 4 fp32 accumulator

__device__ __forceinline__ float lrelu(float v) { return v > 0.f ? v : SLOPE * v; }
__device__ __forceinline__ unsigned int flipf(float x) {
    unsigned int u = __float_as_uint(x);
    return (u & 0x80000000u) ? ~u : (u | 0x80000000u);
}
__device__ __forceinline__ float unflipf(unsigned int u) {
    return __uint_as_float((u & 0x80000000u) ? (u & 0x7fffffffu) : ~u);
}
__device__ __forceinline__ short f2bs(float v) {
    __hip_bfloat16 h = __float2bfloat16(v);
    return *reinterpret_cast<short*>(&h);
}
__device__ __forceinline__ float bs2f(short s) {
    __hip_bfloat16 h = *reinterpret_cast<__hip_bfloat16*>(&s);
    return __bfloat162float(h);
}

// ---------------- zero scratch (replaces 7 memsets with 1 launch) -------------
__global__ void zero_kernel(float* __restrict__ p, int n) {
    int i = blockIdx.x * 256 + threadIdx.x;
    if (i < n) p[i] = 0.f;
}

// ------- weight prep: WT1[c][k] = (w1@enc_w)[c,k]  (c-major), bc1 = w1@enc_b --
__global__ void prep_weights(const float* __restrict__ enc_w,
                             const float* __restrict__ enc_b,
                             const float* __restrict__ w1,
                             const float* __restrict__ w2,
                             float* __restrict__ WT1, float* __restrict__ WT2,
                             float* __restrict__ bc1, float* __restrict__ bc2) {
    int c = blockIdx.x;   // 128 blocks (output channel)
    int k = threadIdx.x;  // 128 threads (input channel)
    __shared__ float w1row[128];
    w1row[k] = w1[c * 128 + k];
    __syncthreads();
    float acc = 0.f;
    for (int j = 0; j < 128; ++j)
        acc = fmaf(w1row[j], enc_w[j * 128 + k], acc);
    WT1[c * 128 + k] = acc;          // c-major for MFMA B staging
    WT2[c * 128 + k] = w2[c * 128 + k];
    if (k == 0) {
        float b = 0.f;
        for (int j = 0; j < 128; ++j) b += w1row[j] * enc_b[j];
        bc1[c] = b;
        bc2[c] = 0.f;
    }
}

// ---------------- CSR build ----------------
__global__ void count_deg(const int* __restrict__ ei, int* __restrict__ deg, int E, int N) {
    int e = blockIdx.x * 256 + threadIdx.x;
    if (e >= E + N) return;
    int dst = (e < E) ? ei[E + e] : (e - E);
    atomicAdd(&deg[dst], 1);
}

__global__ void scan_block_sums(const int* __restrict__ deg, int* __restrict__ part, int N) {
    __shared__ int sh[256];
    int t = threadIdx.x;
    int i = blockIdx.x * 256 + t;
    sh[t] = (i < N) ? deg[i] : 0;
    __syncthreads();
    for (int off = 128; off; off >>= 1) {
        if (t < off) sh[t] += sh[t + off];
        __syncthreads();
    }
    if (t == 0) part[blockIdx.x] = sh[0];
}

__global__ void scan_partials(int* __restrict__ part, int nb) {
    __shared__ int sh[1024];
    int t = threadIdx.x;
    int v = (t < nb) ? part[t] : 0;
    sh[t] = v;
    __syncthreads();
    for (int off = 1; off < 1024; off <<= 1) {
        int add = (t >= off) ? sh[t - off] : 0;
        __syncthreads();
        sh[t] += add;
        __syncthreads();
    }
    if (t < nb) part[t] = sh[t] - v;  // exclusive
}

__global__ void scan_write(const int* __restrict__ deg, const int* __restrict__ part,
                           int* __restrict__ row, int* __restrict__ cursor, int N, int Etot) {
    __shared__ int sh[256];
    int t = threadIdx.x;
    int i = blockIdx.x * 256 + t;
    int v = (i < N) ? deg[i] : 0;
    sh[t] = v;
    __syncthreads();
    for (int off = 1; off < 256; off <<= 1) {
        int add = (t >= off) ? sh[t - off] : 0;
        __syncthreads();
        sh[t] += add;
        __syncthreads();
    }
    int excl = sh[t] - v + part[blockIdx.x];
    if (i < N) { row[i] = excl; cursor[i] = excl; }
    if (i == 0 && blockIdx.x == 0) row[N] = Etot;
}

__global__ void scatter_edges(const int* __restrict__ ei, int* __restrict__ cursor,
                              int* __restrict__ esrc, int E, int N) {
    int e = blockIdx.x * 256 + threadIdx.x;
    if (e >= E + N) return;
    int src, dst;
    if (e < E) { src = ei[e]; dst = ei[E + e]; } else { src = dst = e - E; }
    int pos = atomicAdd(&cursor[dst], 1);
    esrc[pos] = src;
}

// --------- MFMA GEMM: H[n][128] (bf16) = act(A[n][128]) @ WT^T + bc; + scores --
// block = 256 thr = 4 waves, 64 nodes/block, wave -> 16 nodes.
// A/B layouts (HW-verified m89/m91/m118): A[m=lane&15][k=quad*8+j],
// B[k=quad*8+j][n=lane&15], C col=lane&15 row=quad*4+reg.
// Optional fused GraphNorm on input: v = v*Ac[g][c] + Bc[g][c]  (layer 2).
__global__ void __launch_bounds__(256) gemm_mfma(
    const float* __restrict__ A, const float* __restrict__ WT,
    const float* __restrict__ bias, const float* __restrict__ att_src,
    const float* __restrict__ att_dst, const int* __restrict__ batch,
    const float* __restrict__ Ac, const float* __restrict__ Bc,
    unsigned int* __restrict__ H, float* __restrict__ ssrc, float* __restrict__ sdst, int N) {
    __shared__ short Bsh[128 * APITCH];  // 34816 B, [c][k] bf16
    __shared__ short Ash[64 * APITCH];   // 17408 B, [node][k] bf16 (reused for C)
    __shared__ float asrc_s[128], adst_s[128], bias_s[128];
    int tid = threadIdx.x;
    int base = blockIdx.x * 64;

    // stage B (weights, c-major rows of k)
    for (int idx = tid; idx < 4096; idx += 256) {
        int c = idx >> 5, k4 = (idx & 31) * 4;
        float4 wv = ((const float4*)WT)[idx];
        *(short4*)&Bsh[c * APITCH + k4] =
            make_short4(f2bs(wv.x), f2bs(wv.y), f2bs(wv.z), f2bs(wv.w));
    }
    // stage A (node features, optional fused normalization)
    for (int idx = tid; idx < 2048; idx += 256) {
        int nl = idx >> 5, k4 = (idx & 31) * 4;
        int node = base + nl;
        float4 v = make_float4(0.f, 0.f, 0.f, 0.f);
        if (node < N) {
            v = ((const float4*)A)[node * 32 + (idx & 31)];
            if (Ac) {
                int g = batch[node];
                float4 a4 = *(const float4*)&Ac[g * 128 + k4];
                float4 b4 = *(const float4*)&Bc[g * 128 + k4];
                v.x = fmaf(v.x, a4.x, b4.x);
                v.y = fmaf(v.y, a4.y, b4.y);
                v.z = fmaf(v.z, a4.z, b4.z);
                v.w = fmaf(v.w, a4.w, b4.w);
            }
        }
        *(short4*)&Ash[nl * APITCH + k4] =
            make_short4(f2bs(v.x), f2bs(v.y), f2bs(v.z), f2bs(v.w));
    }
    if (tid < 128) {
        asrc_s[tid] = att_src[tid];
        adst_s[tid] = att_dst[tid];
        bias_s[tid] = bias[tid];
    }
    __syncthreads();

    int w = tid >> 6, lane = tid & 63, col = lane & 15, quad = lane >> 4;
    int rowBase = w * 16;

    bfrag afr[4];
#pragma unroll
    for (int s = 0; s < 4; ++s)
        afr[s] = *(const bfrag*)&Ash[(rowBase + col) * APITCH + s * 32 + quad * 8];

    ffrag acc[8];
#pragma unroll
    for (int t = 0; t < 8; ++t) acc[t] = (ffrag){0.f, 0.f, 0.f, 0.f};

#pragma unroll
    for (int t = 0; t < 8; ++t) {
#pragma unroll
        for (int s = 0; s < 4; ++s) {
            bfrag bfr = *(const bfrag*)&Bsh[(t * 16 + col) * APITCH + s * 32 + quad * 8];
            acc[t] = __builtin_amdgcn_mfma_f32_16x16x32_bf16(afr[s], bfr, acc[t], 0, 0, 0);
        }
    }

    // C (+ folded encoder bias) back into this wave's Ash rows as bf16
#pragma unroll
    for (int t = 0; t < 8; ++t) {
        int ch = t * 16 + col;
        float bv = bias_s[ch];
#pragma unroll
        for (int r = 0; r < 4; ++r)
            Ash[(rowBase + quad * 4 + r) * APITCH + ch] = f2bs(acc[t][r] + bv);
    }
    __syncthreads();

    // coalesced copy-out + attention scores (width-16 shuffle reduce per head)
    float2 av = make_float2(asrc_s[lane * 2], asrc_s[lane * 2 + 1]);
    float2 dv = make_float2(adst_s[lane * 2], adst_s[lane * 2 + 1]);
    for (int r = 0; r < 16; ++r) {
        int node = base + rowBase + r;
        unsigned int hb = *(const unsigned int*)&Ash[(rowBase + r) * APITCH + lane * 2];
        float hx = bs2f((short)(hb & 0xffff));
        float hy = bs2f((short)(hb >> 16));
        float vs = hx * av.x + hy * av.y;
        float vd = hx * dv.x + hy * dv.y;
#pragma unroll
        for (int off = 8; off; off >>= 1) {
            vs += __shfl_xor(vs, off, 16);
            vd += __shfl_xor(vd, off, 16);
        }
        if (node < N) {
            H[node * 64 + lane] = hb;  // bf162: channels 2*lane, 2*lane+1
            if ((lane & 15) == 0) {
                int h = lane >> 4;
                ssrc[node * 4 + h] = vs;
                sdst[node * 4 + h] = vd;
            }
        }
    }
}

// ------- aggregation: per-dst softmax (no max pass; scores |e|<~15) + sum -----
__global__ void __launch_bounds__(256) agg_kernel(
    const int* __restrict__ row, const int* __restrict__ esrc,
    const float* __restrict__ ssrc, const float* __restrict__ sdst,
    const __hip_bfloat162* __restrict__ H, const float* __restrict__ bias,
    float* __restrict__ out, int N) {
    int n = (blockIdx.x * 256 + threadIdx.x) >> 6;
    int lane = threadIdx.x & 63;
    if (n >= N) return;
    int beg = row[n], end = row[n + 1];
    float4 sd = ((const float4*)sdst)[n];

    // denominator pass (exp(e)/sum(exp(e)) == softmax; max-shift cancels exactly)
    float d0 = 0.f, d1 = 0.f, d2 = 0.f, d3 = 0.f;
    for (int e = beg + lane; e < end; e += 64) {
        int s = esrc[e];
        float4 ss = ((const float4*)ssrc)[s];
        d0 += __expf(lrelu(ss.x + sd.x));
        d1 += __expf(lrelu(ss.y + sd.y));
        d2 += __expf(lrelu(ss.z + sd.z));
        d3 += __expf(lrelu(ss.w + sd.w));
    }
#pragma unroll
    for (int off = 32; off; off >>= 1) {
        d0 += __shfl_xor(d0, off);
        d1 += __shfl_xor(d1, off);
        d2 += __shfl_xor(d2, off);
        d3 += __shfl_xor(d3, off);
    }
    // weighted-sum pass: lane owns channels 2*lane, 2*lane+1 (head = lane>>4)
    int hh = lane >> 4;
    float dh = hh < 2 ? (hh == 0 ? d0 : d1) : (hh == 2 ? d2 : d3);
    float sdh = hh < 2 ? (hh == 0 ? sd.x : sd.y) : (hh == 2 ? sd.z : sd.w);
    float rh = 1.f / dh;
    int c0 = lane * 2;
    float a0 = 0.f, a1 = 0.f;
    for (int e = beg; e < end; ++e) {
        int s = esrc[e];
        float al = __expf(lrelu(ssrc[s * 4 + hh] + sdh)) * rh;
        float2 hv = __bfloat1622float2(H[s * 64 + lane]);
        a0 = fmaf(al, hv.x, a0);
        a1 = fmaf(al, hv.y, a1);
    }
    a0 += bias[c0];
    a1 += bias[c0 + 1];
    a0 = a0 > 0.f ? a0 : __expf(a0) - 1.f;  // ELU
    a1 = a1 > 0.f ? a1 : __expf(a1) - 1.f;
    ((float2*)out)[n * 64 + lane] = make_float2(a0, a1);
}

// ---------------- GraphNorm ----------------
__global__ void norm_stats(const float* __restrict__ X, const int* __restrict__ batch,
                           float* __restrict__ gsum, float* __restrict__ gsq,
                           int* __restrict__ gcnt, int N, int countFlag) {
    int c = threadIdx.x;  // 128
    int base = blockIdx.x * 64;
    if (base >= N) return;
    int end = min(base + 64, N);
    int cur = batch[base];
    float s = 0.f, q = 0.f;
    int cnt = 0;
    for (int n = base; n < end; ++n) {
        int g = batch[n];
        if (g != cur) {
            atomicAdd(&gsum[cur * 128 + c], s);
            atomicAdd(&gsq[cur * 128 + c], q);
            if (c == 0 && countFlag) atomicAdd(&gcnt[cur], cnt);
            s = 0.f; q = 0.f; cnt = 0; cur = g;
        }
        float v = X[n * 128 + c];
        s += v;
        q += v * v;
        ++cnt;
    }
    atomicAdd(&gsum[cur * 128 + c], s);
    atomicAdd(&gsq[cur * 128 + c], q);
    if (c == 0 && countFlag) atomicAdd(&gcnt[cur], cnt);
}

__global__ void norm_coef(const float* __restrict__ gsum, const float* __restrict__ gsq,
                          const int* __restrict__ gcnt,
                          const float* __restrict__ w, const float* __restrict__ b,
                          const float* __restrict__ ms,
                          float* __restrict__ Ac, float* __restrict__ Bc) {
    int g = blockIdx.x, c = threadIdx.x;
    int i = g * 128 + c;
    float cntv = (float)gcnt[g];
    if (cntv < 0.5f) { Ac[i] = 0.f; Bc[i] = 0.f; return; }
    float mean = gsum[i] / cntv;
    float msv = ms[c];
    float var = gsq[i] / cntv - msv * (2.f - msv) * mean * mean;
    var = fmaxf(var, 0.f);
    float inv = rsqrtf(var + EPS_GN);
    float wv = w[c];
    Ac[i] = wv * inv;
    Bc[i] = b[c] - msv * mean * wv * inv;
}

// layer-2 normalize fused with segment-max pooling (flip-encoded atomicMax)
__global__ void norm_pool(const float* __restrict__ X, const int* __restrict__ batch,
                          const float* __restrict__ Ac, const float* __restrict__ Bc,
                          unsigned int* __restrict__ pool, int N) {
    int c = threadIdx.x;  // 128
    int base = blockIdx.x * 64;
    if (base >= N) return;
    int end = min(base + 64, N);
    int cur = batch[base];
    float mx = -3e38f;
    for (int n = base; n < end; ++n) {
        int g = batch[n];
        if (g != cur) {
            atomicMax(&pool[cur * 128 + c], flipf(mx));
            mx = -3e38f;
            cur = g;
        }
        float v = fmaf(X[n * 128 + c], Ac[g * 128 + c], Bc[g * 128 + c]);
        mx = fmaxf(mx, v);
    }
    atomicMax(&pool[cur * 128 + c], flipf(mx));
}

// ---------------- FC: out[g][o] = pooled[g] . fc_w[o] + fc_b[o] --------------
__global__ void fc_kernel(const unsigned int* __restrict__ pool,
                          const float* __restrict__ fcw,
                          const float* __restrict__ fcb,
                          float* __restrict__ out) {
    int g = blockIdx.x, o = threadIdx.x;  // 64 x 64
    __shared__ float p[128];
    p[o] = unflipf(pool[g * 128 + o]);
    p[o + 64] = unflipf(pool[g * 128 + 64 + o]);
    __syncthreads();
    float acc = fcb[o];
    for (int k = 0; k < 128; ++k)
        acc = fmaf(p[k], fcw[o * 128 + k], acc);
    out[g * 64 + o] = acc;
}

extern "C" void kernel_launch(void* const* d_in, const int* in_sizes, int n_in,
                              void* d_out, int out_size, void* d_ws, size_t ws_size,
                              hipStream_t stream) {
    const float* x     = (const float*)d_in[0];
    const int* ei      = (const int*)d_in[1];
    const int* batch   = (const int*)d_in[2];
    const float* enc_w = (const float*)d_in[3];
    const float* enc_b = (const float*)d_in[4];
    const float* w1    = (const float*)d_in[5];
    const float* as1   = (const float*)d_in[6];
    const float* ad1   = (const float*)d_in[7];
    const float* b1    = (const float*)d_in[8];
    const float* n1w   = (const float*)d_in[9];
    const float* n1b   = (const float*)d_in[10];
    const float* n1ms  = (const float*)d_in[11];
    const float* w2    = (const float*)d_in[12];
    const float* as2   = (const float*)d_in[13];
    const float* ad2   = (const float*)d_in[14];
    const float* b2    = (const float*)d_in[15];
    const float* n2w   = (const float*)d_in[16];
    const float* n2b   = (const float*)d_in[17];
    const float* n2ms  = (const float*)d_in[18];
    const float* fcw   = (const float*)d_in[19];
    const float* fcb   = (const float*)d_in[20];
    float* out = (float*)d_out;

    int N = in_sizes[2];
    int E = in_sizes[1] / 2;
    int Etot = E + N;

    char* ws = (char*)d_ws;
    size_t off = 0;
    auto take = [&](size_t bytes) {
        char* p = ws + off;
        off = (off + bytes + 255) & ~(size_t)255;
        return p;
    };
    float* WT1 = (float*)take(128 * 128 * 4);
    float* WT2 = (float*)take(128 * 128 * 4);
    float* bc1 = (float*)take(512);
    float* bc2 = (float*)take(512);
    float* ssrc = (float*)take((size_t)N * 16);
    float* sdst = (float*)take((size_t)N * 16);
    int* rowp   = (int*)take((size_t)(N + 1) * 4);
    int* cursor = (int*)take((size_t)N * 4);
    int* part   = (int*)take(4096 * 4);
    int* esrc   = (int*)take((size_t)Etot * 4);
    unsigned int* H = (unsigned int*)take((size_t)N * 256);  // bf16 [N][128]
    float* AG   = (float*)take((size_t)N * 512);
    float* Ac   = (float*)take(64 * 128 * 4);
    float* Bc   = (float*)take(64 * 128 * 4);
    // --- contiguous zero span (one zero_kernel covers all of these) ---
    size_t zbeg = off;
    int* deg     = (int*)take((size_t)N * 4);
    float* gsumA = (float*)take(64 * 128 * 4);
    float* gsqA  = (float*)take(64 * 128 * 4);
    float* gsumB = (float*)take(64 * 128 * 4);
    float* gsqB  = (float*)take(64 * 128 * 4);
    int* gcnt    = (int*)take(256);
    unsigned int* pool = (unsigned int*)take(64 * 128 * 4);
    size_t zend = off;
    if (off > ws_size) return;  // workspace too small -> output stays zero

    int zn = (int)((zend - zbeg) / 4);
    int NB = (N + 255) / 256;

    zero_kernel<<<(zn + 255) / 256, 256, 0, stream>>>((float*)(ws + zbeg), zn);
    prep_weights<<<128, 128, 0, stream>>>(enc_w, enc_b, w1, w2, WT1, WT2, bc1, bc2);

    count_deg<<<(Etot + 255) / 256, 256, 0, stream>>>(ei, deg, E, N);
    scan_block_sums<<<NB, 256, 0, stream>>>(deg, part, N);
    scan_partials<<<1, 1024, 0, stream>>>(part, NB);
    scan_write<<<NB, 256, 0, stream>>>(deg, part, rowp, cursor, N, Etot);
    scatter_edges<<<(Etot + 255) / 256, 256, 0, stream>>>(ei, cursor, esrc, E, N);

    // ---- layer 1 (encoder folded into WT1/bc1) ----
    gemm_mfma<<<(N + 63) / 64, 256, 0, stream>>>(x, WT1, bc1, as1, ad1, batch,
                                                 nullptr, nullptr, H, ssrc, sdst, N);
    agg_kernel<<<(N + 3) / 4, 256, 0, stream>>>(rowp, esrc, ssrc, sdst,
                                                (const __hip_bfloat162*)H, b1, AG, N);
    norm_stats<<<(N + 63) / 64, 128, 0, stream>>>(AG, batch, gsumA, gsqA, gcnt, N, 1);
    norm_coef<<<64, 128, 0, stream>>>(gsumA, gsqA, gcnt, n1w, n1b, n1ms, Ac, Bc);

    // ---- layer 2 (GraphNorm fused into gemm A-staging) ----
    gemm_mfma<<<(N + 63) / 64, 256, 0, stream>>>(AG, WT2, bc2, as2, ad2, batch,
                                                 Ac, Bc, H, ssrc, sdst, N);
    agg_kernel<<<(N + 3) / 4, 256, 0, stream>>>(rowp, esrc, ssrc, sdst,
                                                (const __hip_bfloat162*)H, b2, AG, N);
    norm_stats<<<(N + 63) / 64, 128, 0, stream>>>(AG, batch, gsumB, gsqB, gcnt, N, 0);
    norm_coef<<<64, 128, 0, stream>>>(gsumB, gsqB, gcnt, n2w, n2b, n2ms, Ac, Bc);
    norm_pool<<<(N + 63) / 64, 128, 0, stream>>>(AG, batch, Ac, Bc, pool, N);

    fc_kernel<<<64, 64, 0, stream>>>(pool, fcw, fcb, out);
}

// Round 4
// 617.050 us; speedup vs baseline: 1.8871x; 1.3811x over previous
//
#include <hip/hip_runtime.h>
#include <hip/hip_bf16.h>

#define SLOPE 0.2f
#define EPS_GN 1e-5f
#define APITCH 136  // LDS row pitch in bf16 elements (272 B): 16B-aligned, breaks power-of-2 bank aliasing

typedef __attribute__((ext_vector_type(8))) short bfrag;   // 8 bf16 = 4 VGPR (MFMA A/B operand)
typedef __attribute__((ext_vector_type(4))) float ffrag;   // 4 fp32 accumulator

__device__ __forceinline__ float lrelu(float v) { return v > 0.f ? v : SLOPE * v; }
__device__ __forceinline__ unsigned int flipf(float x) {
    unsigned int u = __float_as_uint(x);
    return (u & 0x80000000u) ? ~u : (u | 0x80000000u);
}
__device__ __forceinline__ float unflipf(unsigned int u) {
    return __uint_as_float((u & 0x80000000u) ? (u & 0x7fffffffu) : ~u);
}
__device__ __forceinline__ short f2bs(float v) {
    __hip_bfloat16 h = __float2bfloat16(v);
    return *reinterpret_cast<short*>(&h);
}
__device__ __forceinline__ float bs2f(short s) {
    __hip_bfloat16 h = *reinterpret_cast<__hip_bfloat16*>(&s);
    return __bfloat162float(h);
}
__device__ __forceinline__ float blo(unsigned int u) { return __uint_as_float(u << 16); }
__device__ __forceinline__ float bhi(unsigned int u) { return __uint_as_float(u & 0xffff0000u); }

// ---------------- zero scratch ----------------
__global__ void zero_kernel(float* __restrict__ p, int n) {
    int i = blockIdx.x * 256 + threadIdx.x;
    if (i < n) p[i] = 0.f;
}

// ------- weight prep: WT1[c][k] = (w1@enc_w)[c,k]  (c-major), bc1 = w1@enc_b --
__global__ void prep_weights(const float* __restrict__ enc_w,
                             const float* __restrict__ enc_b,
                             const float* __restrict__ w1,
                             const float* __restrict__ w2,
                             float* __restrict__ WT1, float* __restrict__ WT2,
                             float* __restrict__ bc1, float* __restrict__ bc2) {
    int c = blockIdx.x;   // 128 blocks (output channel)
    int k = threadIdx.x;  // 128 threads (input channel)
    __shared__ float w1row[128];
    w1row[k] = w1[c * 128 + k];
    __syncthreads();
    float acc = 0.f;
    for (int j = 0; j < 128; ++j)
        acc = fmaf(w1row[j], enc_w[j * 128 + k], acc);
    WT1[c * 128 + k] = acc;          // c-major for MFMA B staging
    WT2[c * 128 + k] = w2[c * 128 + k];
    if (k == 0) {
        float b = 0.f;
        for (int j = 0; j < 128; ++j) b += w1row[j] * enc_b[j];
        bc1[c] = b;
        bc2[c] = 0.f;
    }
}

// ---------------- CSR build ----------------
__global__ void count_deg(const int* __restrict__ ei, int* __restrict__ deg, int E, int N) {
    int e = blockIdx.x * 256 + threadIdx.x;
    if (e >= E + N) return;
    int dst = (e < E) ? ei[E + e] : (e - E);
    atomicAdd(&deg[dst], 1);
}

__global__ void scan_block_sums(const int* __restrict__ deg, int* __restrict__ part, int N) {
    __shared__ int sh[256];
    int t = threadIdx.x;
    int i = blockIdx.x * 256 + t;
    sh[t] = (i < N) ? deg[i] : 0;
    __syncthreads();
    for (int off = 128; off; off >>= 1) {
        if (t < off) sh[t] += sh[t + off];
        __syncthreads();
    }
    if (t == 0) part[blockIdx.x] = sh[0];
}

__global__ void scan_partials(int* __restrict__ part, int nb) {
    __shared__ int sh[1024];
    int t = threadIdx.x;
    int v = (t < nb) ? part[t] : 0;
    sh[t] = v;
    __syncthreads();
    for (int off = 1; off < 1024; off <<= 1) {
        int add = (t >= off) ? sh[t - off] : 0;
        __syncthreads();
        sh[t] += add;
        __syncthreads();
    }
    if (t < nb) part[t] = sh[t] - v;  // exclusive
}

__global__ void scan_write(const int* __restrict__ deg, const int* __restrict__ part,
                           int* __restrict__ row, int* __restrict__ cursor, int N, int Etot) {
    __shared__ int sh[256];
    int t = threadIdx.x;
    int i = blockIdx.x * 256 + t;
    int v = (i < N) ? deg[i] : 0;
    sh[t] = v;
    __syncthreads();
    for (int off = 1; off < 256; off <<= 1) {
        int add = (t >= off) ? sh[t - off] : 0;
        __syncthreads();
        sh[t] += add;
        __syncthreads();
    }
    int excl = sh[t] - v + part[blockIdx.x];
    if (i < N) { row[i] = excl; cursor[i] = excl; }
    if (i == 0 && blockIdx.x == 0) row[N] = Etot;
}

__global__ void scatter_edges(const int* __restrict__ ei, int* __restrict__ cursor,
                              int* __restrict__ esrc, int E, int N) {
    int e = blockIdx.x * 256 + threadIdx.x;
    if (e >= E + N) return;
    int src, dst;
    if (e < E) { src = ei[e]; dst = ei[E + e]; } else { src = dst = e - E; }
    int pos = atomicAdd(&cursor[dst], 1);
    esrc[pos] = src;
}

// --------- MFMA GEMM: H[n][128] (bf16) = act(A[n][128]) @ WT^T + bc; + scores --
// block = 256 thr = 4 waves, 64 nodes/block, wave -> 16 nodes.
// A/B layouts (HW-verified m89/m91/m118): A[m=lane&15][k=quad*8+j],
// B[k=quad*8+j][n=lane&15], C col=lane&15 row=quad*4+reg.
// If Ac != nullptr: input is bf16 AG with fused GraphNorm v = v*Ac[g][c]+Bc[g][c].
__global__ void __launch_bounds__(256) gemm_mfma(
    const void* __restrict__ Ain, const float* __restrict__ WT,
    const float* __restrict__ bias, const float* __restrict__ att_src,
    const float* __restrict__ att_dst, const int* __restrict__ batch,
    const float* __restrict__ Ac, const float* __restrict__ Bc,
    unsigned int* __restrict__ H, float* __restrict__ ssrc, float* __restrict__ sdst, int N) {
    __shared__ short Bsh[128 * APITCH];  // [c][k] bf16
    __shared__ short Ash[64 * APITCH];   // [node][k] bf16 (reused for C)
    __shared__ float asrc_s[128], adst_s[128], bias_s[128];
    int tid = threadIdx.x;
    int base = blockIdx.x * 64;

    // stage B (weights, c-major rows of k)
    for (int idx = tid; idx < 4096; idx += 256) {
        int c = idx >> 5, k4 = (idx & 31) * 4;
        float4 wv = ((const float4*)WT)[idx];
        *(short4*)&Bsh[c * APITCH + k4] =
            make_short4(f2bs(wv.x), f2bs(wv.y), f2bs(wv.z), f2bs(wv.w));
    }
    // stage A
    if (Ac == nullptr) {
        // fp32 input (layer 1), no norm
        const float* A = (const float*)Ain;
        for (int idx = tid; idx < 2048; idx += 256) {
            int nl = idx >> 5, k4 = (idx & 31) * 4;
            int node = base + nl;
            float4 v = make_float4(0.f, 0.f, 0.f, 0.f);
            if (node < N) v = ((const float4*)A)[node * 32 + (idx & 31)];
            *(short4*)&Ash[nl * APITCH + k4] =
                make_short4(f2bs(v.x), f2bs(v.y), f2bs(v.z), f2bs(v.w));
        }
    } else {
        // bf16 input (layer 2) with fused GraphNorm
        const uint4* A4 = (const uint4*)Ain;
        for (int idx = tid; idx < 1024; idx += 256) {
            int nl = idx >> 4, u4 = idx & 15, k8 = u4 * 8;
            int node = base + nl;
            short o[8] = {0, 0, 0, 0, 0, 0, 0, 0};
            if (node < N) {
                uint4 hb = A4[node * 16 + u4];
                int g = batch[node];
                float4 a0 = *(const float4*)&Ac[g * 128 + k8];
                float4 a1 = *(const float4*)&Ac[g * 128 + k8 + 4];
                float4 b0 = *(const float4*)&Bc[g * 128 + k8];
                float4 b1 = *(const float4*)&Bc[g * 128 + k8 + 4];
                o[0] = f2bs(fmaf(blo(hb.x), a0.x, b0.x));
                o[1] = f2bs(fmaf(bhi(hb.x), a0.y, b0.y));
                o[2] = f2bs(fmaf(blo(hb.y), a0.z, b0.z));
                o[3] = f2bs(fmaf(bhi(hb.y), a0.w, b0.w));
                o[4] = f2bs(fmaf(blo(hb.z), a1.x, b1.x));
                o[5] = f2bs(fmaf(bhi(hb.z), a1.y, b1.y));
                o[6] = f2bs(fmaf(blo(hb.w), a1.z, b1.z));
                o[7] = f2bs(fmaf(bhi(hb.w), a1.w, b1.w));
            }
            *(bfrag*)&Ash[nl * APITCH + k8] = *(bfrag*)o;
        }
    }
    if (tid < 128) {
        asrc_s[tid] = att_src[tid];
        adst_s[tid] = att_dst[tid];
        bias_s[tid] = bias[tid];
    }
    __syncthreads();

    int w = tid >> 6, lane = tid & 63, col = lane & 15, quad = lane >> 4;
    int rowBase = w * 16;

    bfrag afr[4];
#pragma unroll
    for (int s = 0; s < 4; ++s)
        afr[s] = *(const bfrag*)&Ash[(rowBase + col) * APITCH + s * 32 + quad * 8];

    ffrag acc[8];
#pragma unroll
    for (int t = 0; t < 8; ++t) acc[t] = (ffrag){0.f, 0.f, 0.f, 0.f};

#pragma unroll
    for (int t = 0; t < 8; ++t) {
#pragma unroll
        for (int s = 0; s < 4; ++s) {
            bfrag bfr = *(const bfrag*)&Bsh[(t * 16 + col) * APITCH + s * 32 + quad * 8];
            acc[t] = __builtin_amdgcn_mfma_f32_16x16x32_bf16(afr[s], bfr, acc[t], 0, 0, 0);
        }
    }

    // C (+ folded bias) back into this wave's Ash rows as bf16
#pragma unroll
    for (int t = 0; t < 8; ++t) {
        int ch = t * 16 + col;
        float bv = bias_s[ch];
#pragma unroll
        for (int r = 0; r < 4; ++r)
            Ash[(rowBase + quad * 4 + r) * APITCH + ch] = f2bs(acc[t][r] + bv);
    }
    __syncthreads();

    // coalesced copy-out + attention scores (width-16 shuffle reduce per head)
    float2 av = make_float2(asrc_s[lane * 2], asrc_s[lane * 2 + 1]);
    float2 dv = make_float2(adst_s[lane * 2], adst_s[lane * 2 + 1]);
    for (int r = 0; r < 16; ++r) {
        int node = base + rowBase + r;
        unsigned int hb = *(const unsigned int*)&Ash[(rowBase + r) * APITCH + lane * 2];
        float hx = blo(hb);
        float hy = bhi(hb);
        float vs = hx * av.x + hy * av.y;
        float vd = hx * dv.x + hy * dv.y;
#pragma unroll
        for (int off = 8; off; off >>= 1) {
            vs += __shfl_xor(vs, off, 16);
            vd += __shfl_xor(vd, off, 16);
        }
        if (node < N) {
            H[node * 64 + lane] = hb;  // bf162: channels 2*lane, 2*lane+1
            if ((lane & 15) == 0) {
                int h = lane >> 4;
                ssrc[node * 4 + h] = vs;
                sdst[node * 4 + h] = vd;
            }
        }
    }
}

// ------- aggregation: single-pass softmax numerator+denominator, wave/node ----
// wave = 4 edge-slots x 16 lanes; lane owns 8 contiguous channels (one head).
// out = bf16 [N][128] with bias+ELU fused.
__global__ void __launch_bounds__(256) agg_kernel(
    const int* __restrict__ row, const int* __restrict__ esrc,
    const float* __restrict__ ssrc, const float* __restrict__ sdst,
    const uint4* __restrict__ H4, const float* __restrict__ bias,
    uint4* __restrict__ out, int N) {
    int n = (blockIdx.x * 256 + threadIdx.x) >> 6;
    int lane = threadIdx.x & 63;
    if (n >= N) return;
    int slot = lane >> 4, li = lane & 15, head = li >> 2;
    int beg = row[n], end = row[n + 1];
    float sdh = sdst[n * 4 + head];

    float num[8] = {0.f, 0.f, 0.f, 0.f, 0.f, 0.f, 0.f, 0.f};
    float den = 0.f;
    for (int e = beg + slot; e < end; e += 4) {
        int s = esrc[e];
        float al = __expf(lrelu(ssrc[s * 4 + head] + sdh));
        uint4 hb = H4[s * 16 + li];
        den += al;
        num[0] = fmaf(al, blo(hb.x), num[0]);
        num[1] = fmaf(al, bhi(hb.x), num[1]);
        num[2] = fmaf(al, blo(hb.y), num[2]);
        num[3] = fmaf(al, bhi(hb.y), num[3]);
        num[4] = fmaf(al, blo(hb.z), num[4]);
        num[5] = fmaf(al, bhi(hb.z), num[5]);
        num[6] = fmaf(al, blo(hb.w), num[6]);
        num[7] = fmaf(al, bhi(hb.w), num[7]);
    }
    // reduce the 4 slots (lanes l, l^16, l^32, l^48 share channels)
    den += __shfl_xor(den, 16);
    den += __shfl_xor(den, 32);
#pragma unroll
    for (int j = 0; j < 8; ++j) {
        num[j] += __shfl_xor(num[j], 16);
        num[j] += __shfl_xor(num[j], 32);
    }
    if (slot == 0) {
        float rh = 1.f / den;
        int c0 = li * 8;
        unsigned int o[4];
#pragma unroll
        for (int p = 0; p < 4; ++p) {
            float v0 = fmaf(num[2 * p], rh, bias[c0 + 2 * p]);
            float v1 = fmaf(num[2 * p + 1], rh, bias[c0 + 2 * p + 1]);
            v0 = v0 > 0.f ? v0 : __expf(v0) - 1.f;  // ELU
            v1 = v1 > 0.f ? v1 : __expf(v1) - 1.f;
            o[p] = ((unsigned int)(unsigned short)f2bs(v0)) |
                   (((unsigned int)(unsigned short)f2bs(v1)) << 16);
        }
        out[n * 16 + li] = make_uint4(o[0], o[1], o[2], o[3]);
    }
}

// ---------------- GraphNorm (bf16 input) ----------------
__global__ void norm_stats(const short* __restrict__ X, const int* __restrict__ batch,
                           float* __restrict__ gsum, float* __restrict__ gsq,
                           int* __restrict__ gcnt, int N, int countFlag) {
    int c = threadIdx.x;  // 128
    int base = blockIdx.x * 64;
    if (base >= N) return;
    int end = min(base + 64, N);
    int cur = batch[base];
    float s = 0.f, q = 0.f;
    int cnt = 0;
    for (int n = base; n < end; ++n) {
        int g = batch[n];
        if (g != cur) {
            atomicAdd(&gsum[cur * 128 + c], s);
            atomicAdd(&gsq[cur * 128 + c], q);
            if (c == 0 && countFlag) atomicAdd(&gcnt[cur], cnt);
            s = 0.f; q = 0.f; cnt = 0; cur = g;
        }
        float v = bs2f(X[n * 128 + c]);
        s += v;
        q += v * v;
        ++cnt;
    }
    atomicAdd(&gsum[cur * 128 + c], s);
    atomicAdd(&gsq[cur * 128 + c], q);
    if (c == 0 && countFlag) atomicAdd(&gcnt[cur], cnt);
}

__global__ void norm_coef(const float* __restrict__ gsum, const float* __restrict__ gsq,
                          const int* __restrict__ gcnt,
                          const float* __restrict__ w, const float* __restrict__ b,
                          const float* __restrict__ ms,
                          float* __restrict__ Ac, float* __restrict__ Bc) {
    int g = blockIdx.x, c = threadIdx.x;
    int i = g * 128 + c;
    float cntv = (float)gcnt[g];
    if (cntv < 0.5f) { Ac[i] = 0.f; Bc[i] = 0.f; return; }
    float mean = gsum[i] / cntv;
    float msv = ms[c];
    float var = gsq[i] / cntv - msv * (2.f - msv) * mean * mean;
    var = fmaxf(var, 0.f);
    float inv = rsqrtf(var + EPS_GN);
    float wv = w[c];
    Ac[i] = wv * inv;
    Bc[i] = b[c] - msv * mean * wv * inv;
}

// layer-2 normalize fused with segment-max pooling (flip-encoded atomicMax)
__global__ void norm_pool(const short* __restrict__ X, const int* __restrict__ batch,
                          const float* __restrict__ Ac, const float* __restrict__ Bc,
                          unsigned int* __restrict__ pool, int N) {
    int c = threadIdx.x;  // 128
    int base = blockIdx.x * 64;
    if (base >= N) return;
    int end = min(base + 64, N);
    int cur = batch[base];
    float mx = -3e38f;
    for (int n = base; n < end; ++n) {
        int g = batch[n];
        if (g != cur) {
            atomicMax(&pool[cur * 128 + c], flipf(mx));
            mx = -3e38f;
            cur = g;
        }
        float v = fmaf(bs2f(X[n * 128 + c]), Ac[g * 128 + c], Bc[g * 128 + c]);
        mx = fmaxf(mx, v);
    }
    atomicMax(&pool[cur * 128 + c], flipf(mx));
}

// ---------------- FC: out[g][o] = pooled[g] . fc_w[o] + fc_b[o] --------------
__global__ void fc_kernel(const unsigned int* __restrict__ pool,
                          const float* __restrict__ fcw,
                          const float* __restrict__ fcb,
                          float* __restrict__ out) {
    int g = blockIdx.x, o = threadIdx.x;  // 64 x 64
    __shared__ float p[128];
    p[o] = unflipf(pool[g * 128 + o]);
    p[o + 64] = unflipf(pool[g * 128 + 64 + o]);
    __syncthreads();
    float acc = fcb[o];
    for (int k = 0; k < 128; ++k)
        acc = fmaf(p[k], fcw[o * 128 + k], acc);
    out[g * 64 + o] = acc;
}

extern "C" void kernel_launch(void* const* d_in, const int* in_sizes, int n_in,
                              void* d_out, int out_size, void* d_ws, size_t ws_size,
                              hipStream_t stream) {
    const float* x     = (const float*)d_in[0];
    const int* ei      = (const int*)d_in[1];
    const int* batch   = (const int*)d_in[2];
    const float* enc_w = (const float*)d_in[3];
    const float* enc_b = (const float*)d_in[4];
    const float* w1    = (const float*)d_in[5];
    const float* as1   = (const float*)d_in[6];
    const float* ad1   = (const float*)d_in[7];
    const float* b1    = (const float*)d_in[8];
    const float* n1w   = (const float*)d_in[9];
    const float* n1b   = (const float*)d_in[10];
    const float* n1ms  = (const float*)d_in[11];
    const float* w2    = (const float*)d_in[12];
    const float* as2   = (const float*)d_in[13];
    const float* ad2   = (const float*)d_in[14];
    const float* b2    = (const float*)d_in[15];
    const float* n2w   = (const float*)d_in[16];
    const float* n2b   = (const float*)d_in[17];
    const float* n2ms  = (const float*)d_in[18];
    const float* fcw   = (const float*)d_in[19];
    const float* fcb   = (const float*)d_in[20];
    float* out = (float*)d_out;

    int N = in_sizes[2];
    int E = in_sizes[1] / 2;
    int Etot = E + N;

    char* ws = (char*)d_ws;
    size_t off = 0;
    auto take = [&](size_t bytes) {
        char* p = ws + off;
        off = (off + bytes + 255) & ~(size_t)255;
        return p;
    };
    float* WT1 = (float*)take(128 * 128 * 4);
    float* WT2 = (float*)take(128 * 128 * 4);
    float* bc1 = (float*)take(512);
    float* bc2 = (float*)take(512);
    float* ssrc = (float*)take((size_t)N * 16);
    float* sdst = (float*)take((size_t)N * 16);
    int* rowp   = (int*)take((size_t)(N + 1) * 4);
    int* cursor = (int*)take((size_t)N * 4);
    int* part   = (int*)take(4096 * 4);
    int* esrc   = (int*)take((size_t)Etot * 4);
    unsigned int* H = (unsigned int*)take((size_t)N * 256);  // bf16 [N][128]
    unsigned int* AG = (unsigned int*)take((size_t)N * 256); // bf16 [N][128]
    float* Ac   = (float*)take(64 * 128 * 4);
    float* Bc   = (float*)take(64 * 128 * 4);
    // --- contiguous zero span (one zero_kernel covers all of these) ---
    size_t zbeg = off;
    int* deg     = (int*)take((size_t)N * 4);
    float* gsumA = (float*)take(64 * 128 * 4);
    float* gsqA  = (float*)take(64 * 128 * 4);
    float* gsumB = (float*)take(64 * 128 * 4);
    float* gsqB  = (float*)take(64 * 128 * 4);
    int* gcnt    = (int*)take(256);
    unsigned int* pool = (unsigned int*)take(64 * 128 * 4);
    size_t zend = off;
    if (off > ws_size) return;  // workspace too small -> output stays zero

    int zn = (int)((zend - zbeg) / 4);
    int NB = (N + 255) / 256;

    zero_kernel<<<(zn + 255) / 256, 256, 0, stream>>>((float*)(ws + zbeg), zn);
    prep_weights<<<128, 128, 0, stream>>>(enc_w, enc_b, w1, w2, WT1, WT2, bc1, bc2);

    count_deg<<<(Etot + 255) / 256, 256, 0, stream>>>(ei, deg, E, N);
    scan_block_sums<<<NB, 256, 0, stream>>>(deg, part, N);
    scan_partials<<<1, 1024, 0, stream>>>(part, NB);
    scan_write<<<NB, 256, 0, stream>>>(deg, part, rowp, cursor, N, Etot);
    scatter_edges<<<(Etot + 255) / 256, 256, 0, stream>>>(ei, cursor, esrc, E, N);

    // ---- layer 1 (encoder folded into WT1/bc1) ----
    gemm_mfma<<<(N + 63) / 64, 256, 0, stream>>>(x, WT1, bc1, as1, ad1, batch,
                                                 nullptr, nullptr, H, ssrc, sdst, N);
    agg_kernel<<<(N + 3) / 4, 256, 0, stream>>>(rowp, esrc, ssrc, sdst,
                                                (const uint4*)H, b1, (uint4*)AG, N);
    norm_stats<<<(N + 63) / 64, 128, 0, stream>>>((const short*)AG, batch, gsumA, gsqA, gcnt, N, 1);
    norm_coef<<<64, 128, 0, stream>>>(gsumA, gsqA, gcnt, n1w, n1b, n1ms, Ac, Bc);

    // ---- layer 2 (GraphNorm fused into gemm A-staging, bf16 input) ----
    gemm_mfma<<<(N + 63) / 64, 256, 0, stream>>>(AG, WT2, bc2, as2, ad2, batch,
                                                 Ac, Bc, H, ssrc, sdst, N);
    agg_kernel<<<(N + 3) / 4, 256, 0, stream>>>(rowp, esrc, ssrc, sdst,
                                                (const uint4*)H, b2, (uint4*)AG, N);
    norm_stats<<<(N + 63) / 64, 128, 0, stream>>>((const short*)AG, batch, gsumB, gsqB, gcnt, N, 0);
    norm_coef<<<64, 128, 0, stream>>>(gsumB, gsqB, gcnt, n2w, n2b, n2ms, Ac, Bc);
    norm_pool<<<(N + 63) / 64, 128, 0, stream>>>((const short*)AG, batch, Ac, Bc, pool, N);

    fc_kernel<<<64, 64, 0, stream>>>(pool, fcw, fcb, out);
}

// Round 5
// 483.833 us; speedup vs baseline: 2.4067x; 1.2753x over previous
//
#include <hip/hip_runtime.h>
#include <hip/hip_bf16.h>

#define SLOPE 0.2f
#define EPS_GN 1e-5f
#define APITCH 136  // LDS row pitch in bf16 elems (272 B): 16B-aligned, breaks power-of-2 bank aliasing
#define NBUCK 391   // ceil(100000/256) dst-buckets of 256 nodes

typedef __attribute__((ext_vector_type(8))) short bfrag;   // 8 bf16 = 4 VGPR (MFMA A/B operand)
typedef __attribute__((ext_vector_type(4))) float ffrag;   // 4 fp32 accumulator

__device__ __forceinline__ float lrelu(float v) { return v > 0.f ? v : SLOPE * v; }
__device__ __forceinline__ unsigned int flipf(float x) {
    unsigned int u = __float_as_uint(x);
    return (u & 0x80000000u) ? ~u : (u | 0x80000000u);
}
__device__ __forceinline__ float unflipf(unsigned int u) {
    return __uint_as_float((u & 0x80000000u) ? (u & 0x7fffffffu) : ~u);
}
__device__ __forceinline__ short f2bs(float v) {
    __hip_bfloat16 h = __float2bfloat16(v);
    return *reinterpret_cast<short*>(&h);
}
__device__ __forceinline__ float bs2f(short s) {
    __hip_bfloat16 h = *reinterpret_cast<__hip_bfloat16*>(&s);
    return __bfloat162float(h);
}
__device__ __forceinline__ float blo(unsigned int u) { return __uint_as_float(u << 16); }
__device__ __forceinline__ float bhi(unsigned int u) { return __uint_as_float(u & 0xffff0000u); }

// ---------------- zero scratch ----------------
__global__ void zero_kernel(float* __restrict__ p, int n) {
    int i = blockIdx.x * 256 + threadIdx.x;
    if (i < n) p[i] = 0.f;
}

// ------- weight prep: WT1b[c][k] = bf16((w1@enc_w)[c,k]), bc1 = w1@enc_b ------
__global__ void prep_weights(const float* __restrict__ enc_w,
                             const float* __restrict__ enc_b,
                             const float* __restrict__ w1,
                             const float* __restrict__ w2,
                             unsigned short* __restrict__ WT1b,
                             unsigned short* __restrict__ WT2b,
                             float* __restrict__ bc1, float* __restrict__ bc2) {
    int c = blockIdx.x;   // 128 blocks (output channel)
    int k = threadIdx.x;  // 128 threads (input channel)
    __shared__ float w1row[128];
    w1row[k] = w1[c * 128 + k];
    __syncthreads();
    float acc = 0.f;
    for (int j = 0; j < 128; ++j)
        acc = fmaf(w1row[j], enc_w[j * 128 + k], acc);
    WT1b[c * 128 + k] = (unsigned short)f2bs(acc);
    WT2b[c * 128 + k] = (unsigned short)f2bs(w2[c * 128 + k]);
    if (k == 0) {
        float b = 0.f;
        for (int j = 0; j < 128; ++j) b += w1row[j] * enc_b[j];
        bc1[c] = b;
        bc2[c] = 0.f;
    }
}

// ============ CSR build: two-level bucketed counting sort =====================
// bucket b = dst >> 8 (256 nodes/bucket). Staged word = (src<<8)|(dst&255).

__global__ void __launch_bounds__(256) bucket_hist(const int* __restrict__ ei,
                                                   int* __restrict__ bhist, int E, int N) {
    __shared__ int h[NBUCK];
    for (int i = threadIdx.x; i < NBUCK; i += 256) h[i] = 0;
    __syncthreads();
    int base = blockIdx.x * 4096;
#pragma unroll
    for (int s = 0; s < 16; ++s) {
        int e = base + s * 256 + threadIdx.x;
        if (e < E + N) {
            int dst = (e < E) ? ei[E + e] : (e - E);
            atomicAdd(&h[dst >> 8], 1);
        }
    }
    __syncthreads();
    for (int i = threadIdx.x; i < NBUCK; i += 256)
        if (h[i]) atomicAdd(&bhist[i], h[i]);
}

__global__ void bucket_scan(const int* __restrict__ bhist,
                            int* __restrict__ bbase, int* __restrict__ bcur) {
    __shared__ int sh[512];
    int t = threadIdx.x;  // 512 threads
    int v = (t < NBUCK) ? bhist[t] : 0;
    sh[t] = v;
    __syncthreads();
    for (int off = 1; off < 512; off <<= 1) {
        int add = (t >= off) ? sh[t - off] : 0;
        __syncthreads();
        sh[t] += add;
        __syncthreads();
    }
    if (t < NBUCK) {
        bbase[t] = sh[t] - v;
        bcur[t] = sh[t] - v;
    }
}

__global__ void __launch_bounds__(256) bucket_scatter(const int* __restrict__ ei,
                                                      int* __restrict__ bcur,
                                                      unsigned int* __restrict__ staging,
                                                      int E, int N) {
    __shared__ int h[NBUCK];
    __shared__ int lb[NBUCK];
    for (int i = threadIdx.x; i < NBUCK; i += 256) h[i] = 0;
    __syncthreads();
    int base = blockIdx.x * 4096;
    int srcv[16], dstv[16];
#pragma unroll
    for (int s = 0; s < 16; ++s) {
        int e = base + s * 256 + threadIdx.x;
        srcv[s] = -1;
        if (e < E + N) {
            srcv[s] = (e < E) ? ei[e] : (e - E);
            dstv[s] = (e < E) ? ei[E + e] : (e - E);
            atomicAdd(&h[dstv[s] >> 8], 1);
        }
    }
    __syncthreads();
    for (int i = threadIdx.x; i < NBUCK; i += 256) {
        int c = h[i];
        lb[i] = c ? atomicAdd(&bcur[i], c) : 0;
        h[i] = 0;  // reuse as within-block cursor
    }
    __syncthreads();
#pragma unroll
    for (int s = 0; s < 16; ++s) {
        if (srcv[s] >= 0) {
            int b = dstv[s] >> 8;
            int slot = atomicAdd(&h[b], 1);
            staging[lb[b] + slot] = ((unsigned int)srcv[s] << 8) | (unsigned int)(dstv[s] & 255);
        }
    }
}

// per-bucket node degrees via LDS histogram (no global atomics)
__global__ void __launch_bounds__(256) bucket_deg(const unsigned int* __restrict__ staging,
                                                  const int* __restrict__ bbase,
                                                  const int* __restrict__ bcur,
                                                  int* __restrict__ deg, int N) {
    int b = blockIdx.x;
    __shared__ int h[256];
    h[threadIdx.x] = 0;
    __syncthreads();
    int s0 = bbase[b], s1 = bcur[b];
    for (int j = s0 + threadIdx.x; j < s1; j += 256)
        atomicAdd(&h[staging[j] & 255], 1);
    __syncthreads();
    int node = b * 256 + threadIdx.x;
    if (node < N) deg[node] = h[threadIdx.x];
}

__global__ void scan_block_sums(const int* __restrict__ deg, int* __restrict__ part, int N) {
    __shared__ int sh[256];
    int t = threadIdx.x;
    int i = blockIdx.x * 256 + t;
    sh[t] = (i < N) ? deg[i] : 0;
    __syncthreads();
    for (int off = 128; off; off >>= 1) {
        if (t < off) sh[t] += sh[t + off];
        __syncthreads();
    }
    if (t == 0) part[blockIdx.x] = sh[0];
}

__global__ void scan_partials(int* __restrict__ part, int nb) {
    __shared__ int sh[1024];
    int t = threadIdx.x;
    int v = (t < nb) ? part[t] : 0;
    sh[t] = v;
    __syncthreads();
    for (int off = 1; off < 1024; off <<= 1) {
        int add = (t >= off) ? sh[t - off] : 0;
        __syncthreads();
        sh[t] += add;
        __syncthreads();
    }
    if (t < nb) part[t] = sh[t] - v;  // exclusive
}

__global__ void scan_write(const int* __restrict__ deg, const int* __restrict__ part,
                           int* __restrict__ row, int N, int Etot) {
    __shared__ int sh[256];
    int t = threadIdx.x;
    int i = blockIdx.x * 256 + t;
    int v = (i < N) ? deg[i] : 0;
    sh[t] = v;
    __syncthreads();
    for (int off = 1; off < 256; off <<= 1) {
        int add = (t >= off) ? sh[t - off] : 0;
        __syncthreads();
        sh[t] += add;
        __syncthreads();
    }
    int excl = sh[t] - v + part[blockIdx.x];
    if (i < N) row[i] = excl;
    if (i == 0 && blockIdx.x == 0) row[N] = Etot;
}

// final CSR scatter: writes land in the bucket's contiguous ~17 KB esrc window
__global__ void __launch_bounds__(256) bucket_csr(const unsigned int* __restrict__ staging,
                                                  const int* __restrict__ bbase,
                                                  const int* __restrict__ bcur,
                                                  const int* __restrict__ rowp,
                                                  int* __restrict__ esrc, int N) {
    int b = blockIdx.x;
    __shared__ int cur[256];
    int node = b * 256 + threadIdx.x;
    cur[threadIdx.x] = (node < N) ? rowp[node] : 0;
    __syncthreads();
    int s0 = bbase[b], s1 = bcur[b];
    for (int j = s0 + threadIdx.x; j < s1; j += 256) {
        unsigned int p = staging[j];
        int pos = atomicAdd(&cur[p & 255], 1);
        esrc[pos] = (int)(p >> 8);
    }
}

// --------- MFMA GEMM: H[n][128] (bf16) = act(A[n][128]) @ WT^T + bc; + scores --
// block = 256 thr = 4 waves, 64 nodes/block, wave -> 16 nodes.
// A/B layouts (HW-verified m89/m91/m118): A[m=lane&15][k=quad*8+j],
// B[k=quad*8+j][n=lane&15], C col=lane&15 row=quad*4+reg.
// If Ac != nullptr: input is bf16 AG with fused GraphNorm v = v*Ac[g][c]+Bc[g][c].
__global__ void __launch_bounds__(256) gemm_mfma(
    const void* __restrict__ Ain, const unsigned short* __restrict__ WTb,
    const float* __restrict__ bias, const float* __restrict__ att_src,
    const float* __restrict__ att_dst, const int* __restrict__ batch,
    const float* __restrict__ Ac, const float* __restrict__ Bc,
    unsigned int* __restrict__ H, float* __restrict__ ssrc, float* __restrict__ sdst, int N) {
    __shared__ short Bsh[128 * APITCH];  // [c][k] bf16
    __shared__ short Ash[64 * APITCH];   // [node][k] bf16 (reused for C)
    __shared__ float asrc_s[128], adst_s[128], bias_s[128];
    int tid = threadIdx.x;
    int base = blockIdx.x * 64;

    // stage B (bf16 weights, c-major rows of k)
    for (int idx = tid; idx < 2048; idx += 256) {
        int c = idx >> 4, k8 = (idx & 15) * 8;
        uint4 wv = ((const uint4*)WTb)[idx];
        *(uint4*)&Bsh[c * APITCH + k8] = wv;
    }
    // stage A
    if (Ac == nullptr) {
        // fp32 input (layer 1), no norm
        const float* A = (const float*)Ain;
        for (int idx = tid; idx < 2048; idx += 256) {
            int nl = idx >> 5, k4 = (idx & 31) * 4;
            int node = base + nl;
            float4 v = make_float4(0.f, 0.f, 0.f, 0.f);
            if (node < N) v = ((const float4*)A)[node * 32 + (idx & 31)];
            *(short4*)&Ash[nl * APITCH + k4] =
                make_short4(f2bs(v.x), f2bs(v.y), f2bs(v.z), f2bs(v.w));
        }
    } else {
        // bf16 input (layer 2) with fused GraphNorm
        const uint4* A4 = (const uint4*)Ain;
        for (int idx = tid; idx < 1024; idx += 256) {
            int nl = idx >> 4, u4 = idx & 15, k8 = u4 * 8;
            int node = base + nl;
            short o[8] = {0, 0, 0, 0, 0, 0, 0, 0};
            if (node < N) {
                uint4 hb = A4[node * 16 + u4];
                int g = batch[node];
                float4 a0 = *(const float4*)&Ac[g * 128 + k8];
                float4 a1 = *(const float4*)&Ac[g * 128 + k8 + 4];
                float4 b0 = *(const float4*)&Bc[g * 128 + k8];
                float4 b1 = *(const float4*)&Bc[g * 128 + k8 + 4];
                o[0] = f2bs(fmaf(blo(hb.x), a0.x, b0.x));
                o[1] = f2bs(fmaf(bhi(hb.x), a0.y, b0.y));
                o[2] = f2bs(fmaf(blo(hb.y), a0.z, b0.z));
                o[3] = f2bs(fmaf(bhi(hb.y), a0.w, b0.w));
                o[4] = f2bs(fmaf(blo(hb.z), a1.x, b1.x));
                o[5] = f2bs(fmaf(bhi(hb.z), a1.y, b1.y));
                o[6] = f2bs(fmaf(blo(hb.w), a1.z, b1.z));
                o[7] = f2bs(fmaf(bhi(hb.w), a1.w, b1.w));
            }
            *(bfrag*)&Ash[nl * APITCH + k8] = *(bfrag*)o;
        }
    }
    if (tid < 128) {
        asrc_s[tid] = att_src[tid];
        adst_s[tid] = att_dst[tid];
        bias_s[tid] = bias[tid];
    }
    __syncthreads();

    int w = tid >> 6, lane = tid & 63, col = lane & 15, quad = lane >> 4;
    int rowBase = w * 16;

    bfrag afr[4];
#pragma unroll
    for (int s = 0; s < 4; ++s)
        afr[s] = *(const bfrag*)&Ash[(rowBase + col) * APITCH + s * 32 + quad * 8];

    ffrag acc[8];
#pragma unroll
    for (int t = 0; t < 8; ++t) acc[t] = (ffrag){0.f, 0.f, 0.f, 0.f};

#pragma unroll
    for (int t = 0; t < 8; ++t) {
#pragma unroll
        for (int s = 0; s < 4; ++s) {
            bfrag bfr = *(const bfrag*)&Bsh[(t * 16 + col) * APITCH + s * 32 + quad * 8];
            acc[t] = __builtin_amdgcn_mfma_f32_16x16x32_bf16(afr[s], bfr, acc[t], 0, 0, 0);
        }
    }

    // C (+ folded bias) back into this wave's Ash rows as bf16
#pragma unroll
    for (int t = 0; t < 8; ++t) {
        int ch = t * 16 + col;
        float bv = bias_s[ch];
#pragma unroll
        for (int r = 0; r < 4; ++r)
            Ash[(rowBase + quad * 4 + r) * APITCH + ch] = f2bs(acc[t][r] + bv);
    }
    __syncthreads();

    // coalesced copy-out + attention scores (width-16 shuffle reduce per head)
    float2 av = make_float2(asrc_s[lane * 2], asrc_s[lane * 2 + 1]);
    float2 dv = make_float2(adst_s[lane * 2], adst_s[lane * 2 + 1]);
    for (int r = 0; r < 16; ++r) {
        int node = base + rowBase + r;
        unsigned int hb = *(const unsigned int*)&Ash[(rowBase + r) * APITCH + lane * 2];
        float hx = blo(hb);
        float hy = bhi(hb);
        float vs = hx * av.x + hy * av.y;
        float vd = hx * dv.x + hy * dv.y;
#pragma unroll
        for (int off = 8; off; off >>= 1) {
            vs += __shfl_xor(vs, off, 16);
            vd += __shfl_xor(vd, off, 16);
        }
        if (node < N) {
            H[node * 64 + lane] = hb;  // bf162: channels 2*lane, 2*lane+1
            if ((lane & 15) == 0) {
                int h = lane >> 4;
                ssrc[node * 4 + h] = vs;
                sdst[node * 4 + h] = vd;
            }
        }
    }
}

// ------- aggregation: single-pass softmax numerator+denominator, wave/node ----
// wave = 4 edge-slots x 16 lanes; lane owns 8 contiguous channels (one head).
// out = bf16 [N][128] with bias+ELU fused.
__global__ void __launch_bounds__(256) agg_kernel(
    const int* __restrict__ row, const int* __restrict__ esrc,
    const float* __restrict__ ssrc, const float* __restrict__ sdst,
    const uint4* __restrict__ H4, const float* __restrict__ bias,
    uint4* __restrict__ out, int N) {
    int n = (blockIdx.x * 256 + threadIdx.x) >> 6;
    int lane = threadIdx.x & 63;
    if (n >= N) return;
    int slot = lane >> 4, li = lane & 15, head = li >> 2;
    int beg = row[n], end = row[n + 1];
    float sdh = sdst[n * 4 + head];

    float num[8] = {0.f, 0.f, 0.f, 0.f, 0.f, 0.f, 0.f, 0.f};
    float den = 0.f;
    for (int e = beg + slot; e < end; e += 4) {
        int s = esrc[e];
        float al = __expf(lrelu(ssrc[s * 4 + head] + sdh));
        uint4 hb = H4[s * 16 + li];
        den += al;
        num[0] = fmaf(al, blo(hb.x), num[0]);
        num[1] = fmaf(al, bhi(hb.x), num[1]);
        num[2] = fmaf(al, blo(hb.y), num[2]);
        num[3] = fmaf(al, bhi(hb.y), num[3]);
        num[4] = fmaf(al, blo(hb.z), num[4]);
        num[5] = fmaf(al, bhi(hb.z), num[5]);
        num[6] = fmaf(al, blo(hb.w), num[6]);
        num[7] = fmaf(al, bhi(hb.w), num[7]);
    }
    // reduce the 4 slots (lanes l, l^16, l^32, l^48 share channels)
    den += __shfl_xor(den, 16);
    den += __shfl_xor(den, 32);
#pragma unroll
    for (int j = 0; j < 8; ++j) {
        num[j] += __shfl_xor(num[j], 16);
        num[j] += __shfl_xor(num[j], 32);
    }
    if (slot == 0) {
        float rh = 1.f / den;
        int c0 = li * 8;
        unsigned int o[4];
#pragma unroll
        for (int p = 0; p < 4; ++p) {
            float v0 = fmaf(num[2 * p], rh, bias[c0 + 2 * p]);
            float v1 = fmaf(num[2 * p + 1], rh, bias[c0 + 2 * p + 1]);
            v0 = v0 > 0.f ? v0 : __expf(v0) - 1.f;  // ELU
            v1 = v1 > 0.f ? v1 : __expf(v1) - 1.f;
            o[p] = ((unsigned int)(unsigned short)f2bs(v0)) |
                   (((unsigned int)(unsigned short)f2bs(v1)) << 16);
        }
        out[n * 16 + li] = make_uint4(o[0], o[1], o[2], o[3]);
    }
}

// ---------------- GraphNorm (bf16 input) ----------------
__global__ void norm_stats(const short* __restrict__ X, const int* __restrict__ batch,
                           float* __restrict__ gsum, float* __restrict__ gsq,
                           int* __restrict__ gcnt, int N, int countFlag) {
    int c = threadIdx.x;  // 128
    int base = blockIdx.x * 64;
    if (base >= N) return;
    int end = min(base + 64, N);
    int cur = batch[base];
    float s = 0.f, q = 0.f;
    int cnt = 0;
    for (int n = base; n < end; ++n) {
        int g = batch[n];
        if (g != cur) {
            atomicAdd(&gsum[cur * 128 + c], s);
            atomicAdd(&gsq[cur * 128 + c], q);
            if (c == 0 && countFlag) atomicAdd(&gcnt[cur], cnt);
            s = 0.f; q = 0.f; cnt = 0; cur = g;
        }
        float v = bs2f(X[n * 128 + c]);
        s += v;
        q += v * v;
        ++cnt;
    }
    atomicAdd(&gsum[cur * 128 + c], s);
    atomicAdd(&gsq[cur * 128 + c], q);
    if (c == 0 && countFlag) atomicAdd(&gcnt[cur], cnt);
}

__global__ void norm_coef(const float* __restrict__ gsum, const float* __restrict__ gsq,
                          const int* __restrict__ gcnt,
                          const float* __restrict__ w, const float* __restrict__ b,
                          const float* __restrict__ ms,
                          float* __restrict__ Ac, float* __restrict__ Bc) {
    int g = blockIdx.x, c = threadIdx.x;
    int i = g * 128 + c;
    float cntv = (float)gcnt[g];
    if (cntv < 0.5f) { Ac[i] = 0.f; Bc[i] = 0.f; return; }
    float mean = gsum[i] / cntv;
    float msv = ms[c];
    float var = gsq[i] / cntv - msv * (2.f - msv) * mean * mean;
    var = fmaxf(var, 0.f);
    float inv = rsqrtf(var + EPS_GN);
    float wv = w[c];
    Ac[i] = wv * inv;
    Bc[i] = b[c] - msv * mean * wv * inv;
}

// layer-2 normalize fused with segment-max pooling (flip-encoded atomicMax)
__global__ void norm_pool(const short* __restrict__ X, const int* __restrict__ batch,
                          const float* __restrict__ Ac, const float* __restrict__ Bc,
                          unsigned int* __restrict__ pool, int N) {
    int c = threadIdx.x;  // 128
    int base = blockIdx.x * 64;
    if (base >= N) return;
    int end = min(base + 64, N);
    int cur = batch[base];
    float mx = -3e38f;
    for (int n = base; n < end; ++n) {
        int g = batch[n];
        if (g != cur) {
            atomicMax(&pool[cur * 128 + c], flipf(mx));
            mx = -3e38f;
            cur = g;
        }
        float v = fmaf(bs2f(X[n * 128 + c]), Ac[g * 128 + c], Bc[g * 128 + c]);
        mx = fmaxf(mx, v);
    }
    atomicMax(&pool[cur * 128 + c], flipf(mx));
}

// ---------------- FC: out[g][o] = pooled[g] . fc_w[o] + fc_b[o] --------------
__global__ void fc_kernel(const unsigned int* __restrict__ pool,
                          const float* __restrict__ fcw,
                          const float* __restrict__ fcb,
                          float* __restrict__ out) {
    int g = blockIdx.x, o = threadIdx.x;  // 64 x 64
    __shared__ float p[128];
    p[o] = unflipf(pool[g * 128 + o]);
    p[o + 64] = unflipf(pool[g * 128 + 64 + o]);
    __syncthreads();
    float acc = fcb[o];
    for (int k = 0; k < 128; ++k)
        acc = fmaf(p[k], fcw[o * 128 + k], acc);
    out[g * 64 + o] = acc;
}

extern "C" void kernel_launch(void* const* d_in, const int* in_sizes, int n_in,
                              void* d_out, int out_size, void* d_ws, size_t ws_size,
                              hipStream_t stream) {
    const float* x     = (const float*)d_in[0];
    const int* ei      = (const int*)d_in[1];
    const int* batch   = (const int*)d_in[2];
    const float* enc_w = (const float*)d_in[3];
    const float* enc_b = (const float*)d_in[4];
    const float* w1    = (const float*)d_in[5];
    const float* as1   = (const float*)d_in[6];
    const float* ad1   = (const float*)d_in[7];
    const float* b1    = (const float*)d_in[8];
    const float* n1w   = (const float*)d_in[9];
    const float* n1b   = (const float*)d_in[10];
    const float* n1ms  = (const float*)d_in[11];
    const float* w2    = (const float*)d_in[12];
    const float* as2   = (const float*)d_in[13];
    const float* ad2   = (const float*)d_in[14];
    const float* b2    = (const float*)d_in[15];
    const float* n2w   = (const float*)d_in[16];
    const float* n2b   = (const float*)d_in[17];
    const float* n2ms  = (const float*)d_in[18];
    const float* fcw   = (const float*)d_in[19];
    const float* fcb   = (const float*)d_in[20];
    float* out = (float*)d_out;

    int N = in_sizes[2];
    int E = in_sizes[1] / 2;
    int Etot = E + N;

    char* ws = (char*)d_ws;
    size_t off = 0;
    auto take = [&](size_t bytes) {
        char* p = ws + off;
        off = (off + bytes + 255) & ~(size_t)255;
        return p;
    };
    unsigned short* WT1b = (unsigned short*)take(128 * 128 * 2);
    unsigned short* WT2b = (unsigned short*)take(128 * 128 * 2);
    float* bc1 = (float*)take(512);
    float* bc2 = (float*)take(512);
    float* ssrc = (float*)take((size_t)N * 16);
    float* sdst = (float*)take((size_t)N * 16);
    int* rowp   = (int*)take((size_t)(N + 1) * 4);
    int* part   = (int*)take(4096 * 4);
    int* esrc   = (int*)take((size_t)Etot * 4);
    unsigned int* staging = (unsigned int*)take((size_t)Etot * 4);
    int* bbase  = (int*)take(512 * 4);
    int* bcur   = (int*)take(512 * 4);
    int* deg    = (int*)take((size_t)N * 4);
    unsigned int* H = (unsigned int*)take((size_t)N * 256);  // bf16 [N][128]
    unsigned int* AG = (unsigned int*)take((size_t)N * 256); // bf16 [N][128]
    float* Ac   = (float*)take(64 * 128 * 4);
    float* Bc   = (float*)take(64 * 128 * 4);
    // --- contiguous zero span (one zero_kernel covers all of these) ---
    size_t zbeg = off;
    int* bhist   = (int*)take(512 * 4);
    float* gsumA = (float*)take(64 * 128 * 4);
    float* gsqA  = (float*)take(64 * 128 * 4);
    float* gsumB = (float*)take(64 * 128 * 4);
    float* gsqB  = (float*)take(64 * 128 * 4);
    int* gcnt    = (int*)take(256);
    unsigned int* pool = (unsigned int*)take(64 * 128 * 4);
    size_t zend = off;
    if (off > ws_size) return;  // workspace too small -> output stays zero

    int zn = (int)((zend - zbeg) / 4);
    int NB = (N + 255) / 256;          // 391 = NBUCK
    int EB = (Etot + 4095) / 4096;

    zero_kernel<<<(zn + 255) / 256, 256, 0, stream>>>((float*)(ws + zbeg), zn);
    prep_weights<<<128, 128, 0, stream>>>(enc_w, enc_b, w1, w2, WT1b, WT2b, bc1, bc2);

    // ---- CSR build (bucketed counting sort) ----
    bucket_hist<<<EB, 256, 0, stream>>>(ei, bhist, E, N);
    bucket_scan<<<1, 512, 0, stream>>>(bhist, bbase, bcur);
    bucket_scatter<<<EB, 256, 0, stream>>>(ei, bcur, staging, E, N);
    bucket_deg<<<NBUCK, 256, 0, stream>>>(staging, bbase, bcur, deg, N);
    scan_block_sums<<<NB, 256, 0, stream>>>(deg, part, N);
    scan_partials<<<1, 1024, 0, stream>>>(part, NB);
    scan_write<<<NB, 256, 0, stream>>>(deg, part, rowp, N, Etot);
    bucket_csr<<<NBUCK, 256, 0, stream>>>(staging, bbase, bcur, rowp, esrc, N);

    // ---- layer 1 (encoder folded into WT1b/bc1) ----
    gemm_mfma<<<(N + 63) / 64, 256, 0, stream>>>(x, WT1b, bc1, as1, ad1, batch,
                                                 nullptr, nullptr, H, ssrc, sdst, N);
    agg_kernel<<<(N + 3) / 4, 256, 0, stream>>>(rowp, esrc, ssrc, sdst,
                                                (const uint4*)H, b1, (uint4*)AG, N);
    norm_stats<<<(N + 63) / 64, 128, 0, stream>>>((const short*)AG, batch, gsumA, gsqA, gcnt, N, 1);
    norm_coef<<<64, 128, 0, stream>>>(gsumA, gsqA, gcnt, n1w, n1b, n1ms, Ac, Bc);

    // ---- layer 2 (GraphNorm fused into gemm A-staging, bf16 input) ----
    gemm_mfma<<<(N + 63) / 64, 256, 0, stream>>>(AG, WT2b, bc2, as2, ad2, batch,
                                                 Ac, Bc, H, ssrc, sdst, N);
    agg_kernel<<<(N + 3) / 4, 256, 0, stream>>>(rowp, esrc, ssrc, sdst,
                                                (const uint4*)H, b2, (uint4*)AG, N);
    norm_stats<<<(N + 63) / 64, 128, 0, stream>>>((const short*)AG, batch, gsumB, gsqB, gcnt, N, 0);
    norm_coef<<<64, 128, 0, stream>>>(gsumB, gsqB, gcnt, n2w, n2b, n2ms, Ac, Bc);
    norm_pool<<<(N + 63) / 64, 128, 0, stream>>>((const short*)AG, batch, Ac, Bc, pool, N);

    fc_kernel<<<64, 64, 0, stream>>>(pool, fcw, fcb, out);
}

// Round 6
// 472.345 us; speedup vs baseline: 2.4652x; 1.0243x over previous
//
#include <hip/hip_runtime.h>
#include <hip/hip_bf16.h>

#define SLOPE 0.2f
#define EPS_GN 1e-5f
#define APITCH 136  // LDS row pitch in bf16 elems (272 B): 16B-aligned, breaks power-of-2 bank aliasing
#define NBUCK 391   // ceil(100000/256) dst-buckets of 256 nodes

typedef __attribute__((ext_vector_type(8))) short bfrag;   // 8 bf16 = 4 VGPR (MFMA A/B operand)
typedef __attribute__((ext_vector_type(4))) float ffrag;   // 4 fp32 accumulator

__device__ __forceinline__ float lrelu(float v) { return v > 0.f ? v : SLOPE * v; }
__device__ __forceinline__ unsigned int flipf(float x) {
    unsigned int u = __float_as_uint(x);
    return (u & 0x80000000u) ? ~u : (u | 0x80000000u);
}
__device__ __forceinline__ float unflipf(unsigned int u) {
    return __uint_as_float((u & 0x80000000u) ? (u & 0x7fffffffu) : ~u);
}
__device__ __forceinline__ short f2bs(float v) {
    __hip_bfloat16 h = __float2bfloat16(v);
    return *reinterpret_cast<short*>(&h);
}
__device__ __forceinline__ float bs2f(short s) {
    __hip_bfloat16 h = *reinterpret_cast<__hip_bfloat16*>(&s);
    return __bfloat162float(h);
}
__device__ __forceinline__ float blo(unsigned int u) { return __uint_as_float(u << 16); }
__device__ __forceinline__ float bhi(unsigned int u) { return __uint_as_float(u & 0xffff0000u); }

// ---------------- zero scratch ----------------
__global__ void zero_kernel(float* __restrict__ p, int n) {
    int i = blockIdx.x * 256 + threadIdx.x;
    if (i < n) p[i] = 0.f;
}

// ------- weight prep: WT1b[c][k] = bf16((w1@enc_w)[c,k]), bc1 = w1@enc_b ------
__global__ void prep_weights(const float* __restrict__ enc_w,
                             const float* __restrict__ enc_b,
                             const float* __restrict__ w1,
                             const float* __restrict__ w2,
                             unsigned short* __restrict__ WT1b,
                             unsigned short* __restrict__ WT2b,
                             float* __restrict__ bc1, float* __restrict__ bc2) {
    int c = blockIdx.x;   // 128 blocks (output channel)
    int k = threadIdx.x;  // 128 threads (input channel)
    __shared__ float w1row[128];
    w1row[k] = w1[c * 128 + k];
    __syncthreads();
    float acc = 0.f;
    for (int j = 0; j < 128; ++j)
        acc = fmaf(w1row[j], enc_w[j * 128 + k], acc);
    WT1b[c * 128 + k] = (unsigned short)f2bs(acc);
    WT2b[c * 128 + k] = (unsigned short)f2bs(w2[c * 128 + k]);
    if (k == 0) {
        float b = 0.f;
        for (int j = 0; j < 128; ++j) b += w1row[j] * enc_b[j];
        bc1[c] = b;
        bc2[c] = 0.f;
    }
}

// ============ CSR build: two-level bucketed counting sort =====================
// bucket b = dst >> 8 (256 nodes/bucket). Staged word = (src<<8)|(dst&255).

__global__ void __launch_bounds__(256) bucket_hist(const int* __restrict__ ei,
                                                   int* __restrict__ bhist, int E, int N) {
    __shared__ int h[NBUCK];
    for (int i = threadIdx.x; i < NBUCK; i += 256) h[i] = 0;
    __syncthreads();
    int base = blockIdx.x * 4096;
#pragma unroll
    for (int s = 0; s < 16; ++s) {
        int e = base + s * 256 + threadIdx.x;
        if (e < E + N) {
            int dst = (e < E) ? ei[E + e] : (e - E);
            atomicAdd(&h[dst >> 8], 1);
        }
    }
    __syncthreads();
    for (int i = threadIdx.x; i < NBUCK; i += 256)
        if (h[i]) atomicAdd(&bhist[i], h[i]);
}

__global__ void bucket_scan(const int* __restrict__ bhist,
                            int* __restrict__ bbase, int* __restrict__ bcur) {
    __shared__ int sh[512];
    int t = threadIdx.x;  // 512 threads
    int v = (t < NBUCK) ? bhist[t] : 0;
    sh[t] = v;
    __syncthreads();
    for (int off = 1; off < 512; off <<= 1) {
        int add = (t >= off) ? sh[t - off] : 0;
        __syncthreads();
        sh[t] += add;
        __syncthreads();
    }
    if (t < NBUCK) {
        bbase[t] = sh[t] - v;
        bcur[t] = sh[t] - v;
    }
}

__global__ void __launch_bounds__(256) bucket_scatter(const int* __restrict__ ei,
                                                      int* __restrict__ bcur,
                                                      unsigned int* __restrict__ staging,
                                                      int E, int N) {
    __shared__ int h[NBUCK];
    __shared__ int lb[NBUCK];
    for (int i = threadIdx.x; i < NBUCK; i += 256) h[i] = 0;
    __syncthreads();
    int base = blockIdx.x * 4096;
    int srcv[16], dstv[16];
#pragma unroll
    for (int s = 0; s < 16; ++s) {
        int e = base + s * 256 + threadIdx.x;
        srcv[s] = -1;
        if (e < E + N) {
            srcv[s] = (e < E) ? ei[e] : (e - E);
            dstv[s] = (e < E) ? ei[E + e] : (e - E);
            atomicAdd(&h[dstv[s] >> 8], 1);
        }
    }
    __syncthreads();
    for (int i = threadIdx.x; i < NBUCK; i += 256) {
        int c = h[i];
        lb[i] = c ? atomicAdd(&bcur[i], c) : 0;
        h[i] = 0;  // reuse as within-block cursor
    }
    __syncthreads();
#pragma unroll
    for (int s = 0; s < 16; ++s) {
        if (srcv[s] >= 0) {
            int b = dstv[s] >> 8;
            int slot = atomicAdd(&h[b], 1);
            staging[lb[b] + slot] = ((unsigned int)srcv[s] << 8) | (unsigned int)(dstv[s] & 255);
        }
    }
}

// fused: per-bucket degree hist -> LDS exclusive scan -> rowp -> CSR scatter.
// Correct because global exscan(deg) == bbase[b] + within-bucket exscan.
__global__ void __launch_bounds__(256) bucket_finalize(
    const unsigned int* __restrict__ staging,
    const int* __restrict__ bbase, const int* __restrict__ bcur,
    int* __restrict__ rowp, int* __restrict__ esrc, int N, int Etot) {
    int b = blockIdx.x, t = threadIdx.x;
    __shared__ int h[256], sc[256];
    h[t] = 0;
    __syncthreads();
    int s0 = bbase[b], s1 = bcur[b];
    for (int j = s0 + t; j < s1; j += 256)
        atomicAdd(&h[staging[j] & 255], 1);
    __syncthreads();
    int d = h[t];
    sc[t] = d;
    __syncthreads();
    for (int off = 1; off < 256; off <<= 1) {
        int add = (t >= off) ? sc[t - off] : 0;
        __syncthreads();
        sc[t] += add;
        __syncthreads();
    }
    int excl = s0 + sc[t] - d;
    int node = b * 256 + t;
    if (node < N) rowp[node] = excl;
    if (b == 0 && t == 0) rowp[N] = Etot;
    __syncthreads();
    h[t] = excl;  // within-bucket cursors
    __syncthreads();
    for (int j = s0 + t; j < s1; j += 256) {
        unsigned int p = staging[j];
        int pos = atomicAdd(&h[p & 255], 1);
        esrc[pos] = (int)(p >> 8);
    }
}

// --------- MFMA GEMM: H[n][128] (bf16) = act(A[n][128]) @ WT^T + bc; + scores --
// block = 256 thr = 4 waves, 64 nodes/block, wave -> 16 nodes.
// A/B layouts (HW-verified m89/m91/m118): A[m=lane&15][k=quad*8+j],
// B[k=quad*8+j][n=lane&15], C col=lane&15 row=quad*4+reg.
// If Ac != nullptr: input is bf16 AG with fused GraphNorm v = v*Ac[g][c]+Bc[g][c].
__global__ void __launch_bounds__(256) gemm_mfma(
    const void* __restrict__ Ain, const unsigned short* __restrict__ WTb,
    const float* __restrict__ bias, const float* __restrict__ att_src,
    const float* __restrict__ att_dst, const int* __restrict__ batch,
    const float* __restrict__ Ac, const float* __restrict__ Bc,
    unsigned int* __restrict__ H, float* __restrict__ ssrc, float* __restrict__ sdst, int N) {
    __shared__ short Bsh[128 * APITCH];  // [c][k] bf16
    __shared__ short Ash[64 * APITCH];   // [node][k] bf16 (reused for C)
    __shared__ float asrc_s[128], adst_s[128], bias_s[128];
    int tid = threadIdx.x;
    int base = blockIdx.x * 64;

    // stage B (bf16 weights, c-major rows of k)
    for (int idx = tid; idx < 2048; idx += 256) {
        int c = idx >> 4, k8 = (idx & 15) * 8;
        uint4 wv = ((const uint4*)WTb)[idx];
        *(uint4*)&Bsh[c * APITCH + k8] = wv;
    }
    // stage A
    if (Ac == nullptr) {
        // fp32 input (layer 1), no norm
        const float* A = (const float*)Ain;
        for (int idx = tid; idx < 2048; idx += 256) {
            int nl = idx >> 5, k4 = (idx & 31) * 4;
            int node = base + nl;
            float4 v = make_float4(0.f, 0.f, 0.f, 0.f);
            if (node < N) v = ((const float4*)A)[node * 32 + (idx & 31)];
            *(short4*)&Ash[nl * APITCH + k4] =
                make_short4(f2bs(v.x), f2bs(v.y), f2bs(v.z), f2bs(v.w));
        }
    } else {
        // bf16 input (layer 2) with fused GraphNorm
        const uint4* A4 = (const uint4*)Ain;
        for (int idx = tid; idx < 1024; idx += 256) {
            int nl = idx >> 4, u4 = idx & 15, k8 = u4 * 8;
            int node = base + nl;
            short o[8] = {0, 0, 0, 0, 0, 0, 0, 0};
            if (node < N) {
                uint4 hb = A4[node * 16 + u4];
                int g = batch[node];
                float4 a0 = *(const float4*)&Ac[g * 128 + k8];
                float4 a1 = *(const float4*)&Ac[g * 128 + k8 + 4];
                float4 b0 = *(const float4*)&Bc[g * 128 + k8];
                float4 b1 = *(const float4*)&Bc[g * 128 + k8 + 4];
                o[0] = f2bs(fmaf(blo(hb.x), a0.x, b0.x));
                o[1] = f2bs(fmaf(bhi(hb.x), a0.y, b0.y));
                o[2] = f2bs(fmaf(blo(hb.y), a0.z, b0.z));
                o[3] = f2bs(fmaf(bhi(hb.y), a0.w, b0.w));
                o[4] = f2bs(fmaf(blo(hb.z), a1.x, b1.x));
                o[5] = f2bs(fmaf(bhi(hb.z), a1.y, b1.y));
                o[6] = f2bs(fmaf(blo(hb.w), a1.z, b1.z));
                o[7] = f2bs(fmaf(bhi(hb.w), a1.w, b1.w));
            }
            *(bfrag*)&Ash[nl * APITCH + k8] = *(bfrag*)o;
        }
    }
    if (tid < 128) {
        asrc_s[tid] = att_src[tid];
        adst_s[tid] = att_dst[tid];
        bias_s[tid] = bias[tid];
    }
    __syncthreads();

    int w = tid >> 6, lane = tid & 63, col = lane & 15, quad = lane >> 4;
    int rowBase = w * 16;

    bfrag afr[4];
#pragma unroll
    for (int s = 0; s < 4; ++s)
        afr[s] = *(const bfrag*)&Ash[(rowBase + col) * APITCH + s * 32 + quad * 8];

    ffrag acc[8];
#pragma unroll
    for (int t = 0; t < 8; ++t) acc[t] = (ffrag){0.f, 0.f, 0.f, 0.f};

#pragma unroll
    for (int t = 0; t < 8; ++t) {
#pragma unroll
        for (int s = 0; s < 4; ++s) {
            bfrag bfr = *(const bfrag*)&Bsh[(t * 16 + col) * APITCH + s * 32 + quad * 8];
            acc[t] = __builtin_amdgcn_mfma_f32_16x16x32_bf16(afr[s], bfr, acc[t], 0, 0, 0);
        }
    }

    // C (+ folded bias) back into this wave's Ash rows as bf16
#pragma unroll
    for (int t = 0; t < 8; ++t) {
        int ch = t * 16 + col;
        float bv = bias_s[ch];
#pragma unroll
        for (int r = 0; r < 4; ++r)
            Ash[(rowBase + quad * 4 + r) * APITCH + ch] = f2bs(acc[t][r] + bv);
    }
    __syncthreads();

    // coalesced copy-out + attention scores (width-16 shuffle reduce per head)
    float2 av = make_float2(asrc_s[lane * 2], asrc_s[lane * 2 + 1]);
    float2 dv = make_float2(adst_s[lane * 2], adst_s[lane * 2 + 1]);
    for (int r = 0; r < 16; ++r) {
        int node = base + rowBase + r;
        unsigned int hb = *(const unsigned int*)&Ash[(rowBase + r) * APITCH + lane * 2];
        float hx = blo(hb);
        float hy = bhi(hb);
        float vs = hx * av.x + hy * av.y;
        float vd = hx * dv.x + hy * dv.y;
#pragma unroll
        for (int off = 8; off; off >>= 1) {
            vs += __shfl_xor(vs, off, 16);
            vd += __shfl_xor(vd, off, 16);
        }
        if (node < N) {
            H[node * 64 + lane] = hb;  // bf162: channels 2*lane, 2*lane+1
            if ((lane & 15) == 0) {
                int h = lane >> 4;
                ssrc[node * 4 + h] = vs;
                sdst[node * 4 + h] = vd;
            }
        }
    }
}

// ------- aggregation: single-pass softmax num+den, software-pipelined ---------
// wave = 4 edge-slots x 16 lanes; lane owns 8 contiguous channels (one head).
// Lookahead-1 on ssrc/H4, lookahead-2 on esrc; branch-free via clamp to end-1.
__global__ void __launch_bounds__(256) agg_kernel(
    const int* __restrict__ row, const int* __restrict__ esrc,
    const float* __restrict__ ssrc, const float* __restrict__ sdst,
    const uint4* __restrict__ H4, const float* __restrict__ bias,
    uint4* __restrict__ out, int N) {
    int n = (blockIdx.x * 256 + threadIdx.x) >> 6;
    int lane = threadIdx.x & 63;
    if (n >= N) return;
    int slot = lane >> 4, li = lane & 15, head = li >> 2;
    int beg = row[n], end = row[n + 1];
    int last = end - 1;
    float sdh = sdst[n * 4 + head];
    int e0 = beg + slot;

    float num[8] = {0.f, 0.f, 0.f, 0.f, 0.f, 0.f, 0.f, 0.f};
    float den = 0.f;

    // prologue: prefetch edge e0 payload and edge e0+4 index (clamped, always valid)
    int sA = esrc[min(e0, last)];
    float svA = ssrc[sA * 4 + head];
    uint4 hbA = H4[sA * 16 + li];
    int sB = esrc[min(e0 + 4, last)];

    for (int e = e0; e < end; e += 4) {
        // prefetch next edge's payload + next-next index
        float svB = ssrc[sB * 4 + head];
        uint4 hbB = H4[sB * 16 + li];
        int sC = esrc[min(e + 8, last)];
        // compute current edge
        float al = __expf(lrelu(svA + sdh));
        den += al;
        num[0] = fmaf(al, blo(hbA.x), num[0]);
        num[1] = fmaf(al, bhi(hbA.x), num[1]);
        num[2] = fmaf(al, blo(hbA.y), num[2]);
        num[3] = fmaf(al, bhi(hbA.y), num[3]);
        num[4] = fmaf(al, blo(hbA.z), num[4]);
        num[5] = fmaf(al, bhi(hbA.z), num[5]);
        num[6] = fmaf(al, blo(hbA.w), num[6]);
        num[7] = fmaf(al, bhi(hbA.w), num[7]);
        // rotate
        svA = svB;
        hbA = hbB;
        sB = sC;
    }
    // reduce the 4 slots (lanes l, l^16, l^32, l^48 share channels)
    den += __shfl_xor(den, 16);
    den += __shfl_xor(den, 32);
#pragma unroll
    for (int j = 0; j < 8; ++j) {
        num[j] += __shfl_xor(num[j], 16);
        num[j] += __shfl_xor(num[j], 32);
    }
    if (slot == 0) {
        float rh = 1.f / den;
        int c0 = li * 8;
        unsigned int o[4];
#pragma unroll
        for (int p = 0; p < 4; ++p) {
            float v0 = fmaf(num[2 * p], rh, bias[c0 + 2 * p]);
            float v1 = fmaf(num[2 * p + 1], rh, bias[c0 + 2 * p + 1]);
            v0 = v0 > 0.f ? v0 : __expf(v0) - 1.f;  // ELU
            v1 = v1 > 0.f ? v1 : __expf(v1) - 1.f;
            o[p] = ((unsigned int)(unsigned short)f2bs(v0)) |
                   (((unsigned int)(unsigned short)f2bs(v1)) << 16);
        }
        out[n * 16 + li] = make_uint4(o[0], o[1], o[2], o[3]);
    }
}

// ---------------- GraphNorm (bf16 input) ----------------
__global__ void norm_stats(const short* __restrict__ X, const int* __restrict__ batch,
                           float* __restrict__ gsum, float* __restrict__ gsq,
                           int* __restrict__ gcnt, int N, int countFlag) {
    int c = threadIdx.x;  // 128
    int base = blockIdx.x * 64;
    if (base >= N) return;
    int end = min(base + 64, N);
    int cur = batch[base];
    float s = 0.f, q = 0.f;
    int cnt = 0;
    for (int n = base; n < end; ++n) {
        int g = batch[n];
        if (g != cur) {
            atomicAdd(&gsum[cur * 128 + c], s);
            atomicAdd(&gsq[cur * 128 + c], q);
            if (c == 0 && countFlag) atomicAdd(&gcnt[cur], cnt);
            s = 0.f; q = 0.f; cnt = 0; cur = g;
        }
        float v = bs2f(X[n * 128 + c]);
        s += v;
        q += v * v;
        ++cnt;
    }
    atomicAdd(&gsum[cur * 128 + c], s);
    atomicAdd(&gsq[cur * 128 + c], q);
    if (c == 0 && countFlag) atomicAdd(&gcnt[cur], cnt);
}

__global__ void norm_coef(const float* __restrict__ gsum, const float* __restrict__ gsq,
                          const int* __restrict__ gcnt,
                          const float* __restrict__ w, const float* __restrict__ b,
                          const float* __restrict__ ms,
                          float* __restrict__ Ac, float* __restrict__ Bc) {
    int g = blockIdx.x, c = threadIdx.x;
    int i = g * 128 + c;
    float cntv = (float)gcnt[g];
    if (cntv < 0.5f) { Ac[i] = 0.f; Bc[i] = 0.f; return; }
    float mean = gsum[i] / cntv;
    float msv = ms[c];
    float var = gsq[i] / cntv - msv * (2.f - msv) * mean * mean;
    var = fmaxf(var, 0.f);
    float inv = rsqrtf(var + EPS_GN);
    float wv = w[c];
    Ac[i] = wv * inv;
    Bc[i] = b[c] - msv * mean * wv * inv;
}

// layer-2 normalize fused with segment-max pooling (flip-encoded atomicMax)
__global__ void norm_pool(const short* __restrict__ X, const int* __restrict__ batch,
                          const float* __restrict__ Ac, const float* __restrict__ Bc,
                          unsigned int* __restrict__ pool, int N) {
    int c = threadIdx.x;  // 128
    int base = blockIdx.x * 64;
    if (base >= N) return;
    int end = min(base + 64, N);
    int cur = batch[base];
    float mx = -3e38f;
    for (int n = base; n < end; ++n) {
        int g = batch[n];
        if (g != cur) {
            atomicMax(&pool[cur * 128 + c], flipf(mx));
            mx = -3e38f;
            cur = g;
        }
        float v = fmaf(bs2f(X[n * 128 + c]), Ac[g * 128 + c], Bc[g * 128 + c]);
        mx = fmaxf(mx, v);
    }
    atomicMax(&pool[cur * 128 + c], flipf(mx));
}

// ---------------- FC: out[g][o] = pooled[g] . fc_w[o] + fc_b[o] --------------
__global__ void fc_kernel(const unsigned int* __restrict__ pool,
                          const float* __restrict__ fcw,
                          const float* __restrict__ fcb,
                          float* __restrict__ out) {
    int g = blockIdx.x, o = threadIdx.x;  // 64 x 64
    __shared__ float p[128];
    p[o] = unflipf(pool[g * 128 + o]);
    p[o + 64] = unflipf(pool[g * 128 + 64 + o]);
    __syncthreads();
    float acc = fcb[o];
    for (int k = 0; k < 128; ++k)
        acc = fmaf(p[k], fcw[o * 128 + k], acc);
    out[g * 64 + o] = acc;
}

extern "C" void kernel_launch(void* const* d_in, const int* in_sizes, int n_in,
                              void* d_out, int out_size, void* d_ws, size_t ws_size,
                              hipStream_t stream) {
    const float* x     = (const float*)d_in[0];
    const int* ei      = (const int*)d_in[1];
    const int* batch   = (const int*)d_in[2];
    const float* enc_w = (const float*)d_in[3];
    const float* enc_b = (const float*)d_in[4];
    const float* w1    = (const float*)d_in[5];
    const float* as1   = (const float*)d_in[6];
    const float* ad1   = (const float*)d_in[7];
    const float* b1    = (const float*)d_in[8];
    const float* n1w   = (const float*)d_in[9];
    const float* n1b   = (const float*)d_in[10];
    const float* n1ms  = (const float*)d_in[11];
    const float* w2    = (const float*)d_in[12];
    const float* as2   = (const float*)d_in[13];
    const float* ad2   = (const float*)d_in[14];
    const float* b2    = (const float*)d_in[15];
    const float* n2w   = (const float*)d_in[16];
    const float* n2b   = (const float*)d_in[17];
    const float* n2ms  = (const float*)d_in[18];
    const float* fcw   = (const float*)d_in[19];
    const float* fcb   = (const float*)d_in[20];
    float* out = (float*)d_out;

    int N = in_sizes[2];
    int E = in_sizes[1] / 2;
    int Etot = E + N;

    char* ws = (char*)d_ws;
    size_t off = 0;
    auto take = [&](size_t bytes) {
        char* p = ws + off;
        off = (off + bytes + 255) & ~(size_t)255;
        return p;
    };
    unsigned short* WT1b = (unsigned short*)take(128 * 128 * 2);
    unsigned short* WT2b = (unsigned short*)take(128 * 128 * 2);
    float* bc1 = (float*)take(512);
    float* bc2 = (float*)take(512);
    float* ssrc = (float*)take((size_t)N * 16);
    float* sdst = (float*)take((size_t)N * 16);
    int* rowp   = (int*)take((size_t)(N + 1) * 4);
    int* esrc   = (int*)take((size_t)Etot * 4);
    unsigned int* staging = (unsigned int*)take((size_t)Etot * 4);
    int* bbase  = (int*)take(512 * 4);
    int* bcur   = (int*)take(512 * 4);
    unsigned int* H = (unsigned int*)take((size_t)N * 256);  // bf16 [N][128]
    unsigned int* AG = (unsigned int*)take((size_t)N * 256); // bf16 [N][128]
    float* Ac   = (float*)take(64 * 128 * 4);
    float* Bc   = (float*)take(64 * 128 * 4);
    // --- contiguous zero span (one zero_kernel covers all of these) ---
    size_t zbeg = off;
    int* bhist   = (int*)take(512 * 4);
    float* gsumA = (float*)take(64 * 128 * 4);
    float* gsqA  = (float*)take(64 * 128 * 4);
    float* gsumB = (float*)take(64 * 128 * 4);
    float* gsqB  = (float*)take(64 * 128 * 4);
    int* gcnt    = (int*)take(256);
    unsigned int* pool = (unsigned int*)take(64 * 128 * 4);
    size_t zend = off;
    if (off > ws_size) return;  // workspace too small -> output stays zero

    int zn = (int)((zend - zbeg) / 4);
    int EB = (Etot + 4095) / 4096;

    zero_kernel<<<(zn + 255) / 256, 256, 0, stream>>>((float*)(ws + zbeg), zn);
    prep_weights<<<128, 128, 0, stream>>>(enc_w, enc_b, w1, w2, WT1b, WT2b, bc1, bc2);

    // ---- CSR build (bucketed counting sort) ----
    bucket_hist<<<EB, 256, 0, stream>>>(ei, bhist, E, N);
    bucket_scan<<<1, 512, 0, stream>>>(bhist, bbase, bcur);
    bucket_scatter<<<EB, 256, 0, stream>>>(ei, bcur, staging, E, N);
    bucket_finalize<<<NBUCK, 256, 0, stream>>>(staging, bbase, bcur, rowp, esrc, N, Etot);

    // ---- layer 1 (encoder folded into WT1b/bc1) ----
    gemm_mfma<<<(N + 63) / 64, 256, 0, stream>>>(x, WT1b, bc1, as1, ad1, batch,
                                                 nullptr, nullptr, H, ssrc, sdst, N);
    agg_kernel<<<(N + 3) / 4, 256, 0, stream>>>(rowp, esrc, ssrc, sdst,
                                                (const uint4*)H, b1, (uint4*)AG, N);
    norm_stats<<<(N + 63) / 64, 128, 0, stream>>>((const short*)AG, batch, gsumA, gsqA, gcnt, N, 1);
    norm_coef<<<64, 128, 0, stream>>>(gsumA, gsqA, gcnt, n1w, n1b, n1ms, Ac, Bc);

    // ---- layer 2 (GraphNorm fused into gemm A-staging, bf16 input) ----
    gemm_mfma<<<(N + 63) / 64, 256, 0, stream>>>(AG, WT2b, bc2, as2, ad2, batch,
                                                 Ac, Bc, H, ssrc, sdst, N);
    agg_kernel<<<(N + 3) / 4, 256, 0, stream>>>(rowp, esrc, ssrc, sdst,
                                                (const uint4*)H, b2, (uint4*)AG, N);
    norm_stats<<<(N + 63) / 64, 128, 0, stream>>>((const short*)AG, batch, gsumB, gsqB, gcnt, N, 0);
    norm_coef<<<64, 128, 0, stream>>>(gsumB, gsqB, gcnt, n2w, n2b, n2ms, Ac, Bc);
    norm_pool<<<(N + 63) / 64, 128, 0, stream>>>((const short*)AG, batch, Ac, Bc, pool, N);

    fc_kernel<<<64, 64, 0, stream>>>(pool, fcw, fcb, out);
}